// Round 1
// baseline (16614.441 us; speedup 1.0000x reference)
//
#include <hip/hip_runtime.h>
#include <hip/hip_bf16.h>

#define Hdim 512
#define Edim 512
#define KR   90
#define BATCH 32
#define SEQ  128
#define VOC  32000

typedef __attribute__((ext_vector_type(8))) short bf16x8;
typedef __attribute__((ext_vector_type(4))) float f32x4;
typedef __attribute__((ext_vector_type(8))) unsigned short u16x8;

__device__ __forceinline__ float b2f(unsigned short u) {
  union { unsigned int i; float f; } w; w.i = ((unsigned int)u) << 16; return w.f;
}
__device__ __forceinline__ unsigned short f2b(float f) {
  __hip_bfloat16 h = __float2bfloat16(f);
  return *reinterpret_cast<unsigned short*>(&h);
}

// ---------------- weight conversion ----------------
// U: [5][512][90] fp32 -> Ut: [5][90][512] bf16 (transposed for contiguous k)
__global__ __launch_bounds__(512) void cvt_transposeU(const float* __restrict__ U,
                                                      unsigned short* __restrict__ Ut) {
  int i = blockIdx.x / KR, j = blockIdx.x % KR;
  int k = threadIdx.x;
  float v = U[((size_t)i * Hdim + k) * KR + j];
  Ut[((size_t)i * KR + j) * Hdim + k] = f2b(v);
}

__global__ __launch_bounds__(256) void cvt_bf16(const float* __restrict__ src,
                                                unsigned short* __restrict__ dst, int n) {
  int i = blockIdx.x * 256 + threadIdx.x;
  if (i < n) dst[i] = f2b(src[i]);
}

// ---------------- mogrifier: one block per batch row ----------------
__global__ __launch_bounds__(256) void mog_kernel(
    const float* __restrict__ emb, const int* __restrict__ tok, int t,
    const float* __restrict__ x_in, const float* __restrict__ h_in,
    const unsigned short* __restrict__ Ut, const unsigned short* __restrict__ Vb,
    const float* __restrict__ bmog,
    float* __restrict__ x_out, float* __restrict__ h_out)
{
  __shared__ float xv[Hdim], hv[Hdim], tp[2][96], tv[96];
  const int b = blockIdx.x, tid = threadIdx.x;
  const float* xsrc = tok ? (emb + (size_t)tok[b * SEQ + t] * Edim)
                          : (x_in + (size_t)b * Hdim);
  for (int i = tid; i < Hdim; i += 256) {
    xv[i] = xsrc[i];
    hv[i] = h_in[(size_t)b * Hdim + i];
  }
  __syncthreads();
  for (int it = 0; it < 5; ++it) {
    float* src = (it & 1) ? xv : hv;   // even it: uses h, updates x
    float* dst = (it & 1) ? hv : xv;
    // stage 1: tv[j] = sum_k src[k] * U[it][k][j]   (Ut is [j][k])
    if (tid < 180) {
      int p = tid / KR, j = tid - p * KR;
      const unsigned short* urow = Ut + ((size_t)it * KR + j) * Hdim + p * 256;
      const float* s = src + p * 256;
      float a0 = 0.f, a1 = 0.f, a2 = 0.f, a3 = 0.f;
      for (int k = 0; k < 256; k += 8) {
        u16x8 u = *reinterpret_cast<const u16x8*>(urow + k);
        a0 += s[k + 0] * b2f(u[0]); a1 += s[k + 1] * b2f(u[1]);
        a2 += s[k + 2] * b2f(u[2]); a3 += s[k + 3] * b2f(u[3]);
        a0 += s[k + 4] * b2f(u[4]); a1 += s[k + 5] * b2f(u[5]);
        a2 += s[k + 6] * b2f(u[6]); a3 += s[k + 7] * b2f(u[7]);
      }
      tp[p][j] = (a0 + a1) + (a2 + a3);
    }
    __syncthreads();
    if (tid < KR) tv[tid] = tp[0][tid] + tp[1][tid];
    __syncthreads();
    // stage 2: dst[col] *= 2*sigmoid(sum_j tv[j]*V[it][j][col] + b[it][col])
    #pragma unroll
    for (int cc = 0; cc < 2; ++cc) {
      int col = tid + cc * 256;
      float acc = bmog[it * Hdim + col];
      const unsigned short* vcol = Vb + (size_t)it * KR * Hdim + col;
      for (int j = 0; j < KR; ++j) acc += tv[j] * b2f(vcol[(size_t)j * Hdim]);
      float gate = 2.0f / (1.0f + expf(-acc));
      dst[col] *= gate;
    }
    __syncthreads();
  }
  for (int i = tid; i < Hdim; i += 256) {
    x_out[(size_t)b * Hdim + i] = xv[i];
    h_out[(size_t)b * Hdim + i] = hv[i];
  }
}

// ---------------- LSTM cell: 256 blocks x 2 cols, gates split across threads ----------------
__global__ __launch_bounds__(256) void lstm_kernel(
    const float* __restrict__ x,   // [32,512]
    const float* __restrict__ hm,  // [32,512]
    float* __restrict__ c,         // [32,512] in/out
    float* __restrict__ h,         // [32,512] out
    const float* __restrict__ Wih, const float* __restrict__ Whh,
    const float* __restrict__ bih, const float* __restrict__ bhh,
    unsigned short* __restrict__ hs, int t)
{
  const int tid = threadIdx.x;
  const int r = tid & 31, cc = (tid >> 5) & 1, G = tid >> 6;
  const int col = blockIdx.x * 2 + cc;
  __shared__ float xs[32][132], hms[32][132];
  __shared__ float gbuf[4][2][32];
  float acc = bih[G * Hdim + col] + bhh[G * Hdim + col];
  const float* wi = Wih + (size_t)(G * Hdim + col) * Hdim;
  const float* wh = Whh + (size_t)(G * Hdim + col) * Hdim;
  for (int k0 = 0; k0 < Hdim; k0 += 128) {
    __syncthreads();
    #pragma unroll
    for (int i = 0; i < 4; ++i) {
      int s = tid + 256 * i;            // 0..1023 float4 slots
      int rr = s >> 5, jj = s & 31;
      float4 xv4 = *reinterpret_cast<const float4*>(x  + (size_t)rr * Hdim + k0 + jj * 4);
      float4 hv4 = *reinterpret_cast<const float4*>(hm + (size_t)rr * Hdim + k0 + jj * 4);
      *reinterpret_cast<float4*>(&xs[rr][jj * 4])  = xv4;
      *reinterpret_cast<float4*>(&hms[rr][jj * 4]) = hv4;
    }
    __syncthreads();
    for (int k = 0; k < 128; k += 4) {
      float4 xv = *reinterpret_cast<const float4*>(&xs[r][k]);
      float4 hv = *reinterpret_cast<const float4*>(&hms[r][k]);
      float4 wiv = *reinterpret_cast<const float4*>(wi + k0 + k);
      float4 whv = *reinterpret_cast<const float4*>(wh + k0 + k);
      acc += xv.x * wiv.x + xv.y * wiv.y + xv.z * wiv.z + xv.w * wiv.w
           + hv.x * whv.x + hv.y * whv.y + hv.z * whv.z + hv.w * whv.w;
    }
  }
  gbuf[G][cc][r] = acc;
  __syncthreads();
  if (tid < 64) {
    int rr = tid & 31, c2 = tid >> 5;
    int col2 = blockIdx.x * 2 + c2;
    float gi = gbuf[0][c2][rr], gf = gbuf[1][c2][rr];
    float gg = gbuf[2][c2][rr], go = gbuf[3][c2][rr];
    float cold = c[(size_t)rr * Hdim + col2];
    float si = 1.f / (1.f + expf(-gi));
    float sf = 1.f / (1.f + expf(-gf));
    float so = 1.f / (1.f + expf(-go));
    float cn = sf * cold + si * tanhf(gg);
    float hn = so * tanhf(cn);
    c[(size_t)rr * Hdim + col2] = cn;
    h[(size_t)rr * Hdim + col2] = hn;
    if (hs) hs[((size_t)rr * SEQ + t) * Hdim + col2] = f2b(hn);
  }
}

// ---------------- output GEMM: logits = hs @ Wout^T + b ----------------
// A: [4096,512] bf16 row-major, B: Wout [32000,512] fp32 row-major (B^T GEMM)
__global__ __launch_bounds__(256) void gemm_out(
    const unsigned short* __restrict__ A,
    const float* __restrict__ Wout,
    const float* __restrict__ bout,
    float* __restrict__ Cmat)
{
  __shared__ unsigned short As[128][72], Bs[128][72];   // +8 bf16 pad keeps 16B align, breaks bank pattern
  const int Mbase = (blockIdx.x & 31) * 128;
  const int Nbase = (blockIdx.x >> 5) * 128;
  const int tid = threadIdx.x, lane = tid & 63, wid = tid >> 6;
  const int wr = wid >> 1, wc = wid & 1;
  f32x4 acc[4][4];
  #pragma unroll
  for (int m = 0; m < 4; ++m)
    #pragma unroll
    for (int n = 0; n < 4; ++n) acc[m][n] = (f32x4){0.f, 0.f, 0.f, 0.f};

  for (int kt = 0; kt < 8; ++kt) {
    const int k0 = kt * 64;
    __syncthreads();
    #pragma unroll
    for (int i = 0; i < 4; ++i) {                 // A tile: 1024 u16x8 slots
      int s = tid + 256 * i;
      int row = s >> 3, c8 = s & 7;
      u16x8 v = *reinterpret_cast<const u16x8*>(A + ((size_t)(Mbase + row)) * Hdim + k0 + c8 * 8);
      *reinterpret_cast<u16x8*>(&As[row][c8 * 8]) = v;
    }
    #pragma unroll
    for (int i = 0; i < 8; ++i) {                 // B tile: 2048 float4 slots, cvt to bf16
      int s = tid + 256 * i;
      int row = s >> 4, c4 = s & 15;
      float4 v = *reinterpret_cast<const float4*>(Wout + ((size_t)(Nbase + row)) * Hdim + k0 + c4 * 4);
      ushort4 b4;
      b4.x = f2b(v.x); b4.y = f2b(v.y); b4.z = f2b(v.z); b4.w = f2b(v.w);
      *reinterpret_cast<ushort4*>(&Bs[row][c4 * 4]) = b4;
    }
    __syncthreads();
    #pragma unroll
    for (int kk = 0; kk < 64; kk += 32) {
      bf16x8 af[4], bfr[4];
      #pragma unroll
      for (int m = 0; m < 4; ++m)
        af[m] = *reinterpret_cast<const bf16x8*>(&As[wr * 64 + m * 16 + (lane & 15)][kk + 8 * (lane >> 4)]);
      #pragma unroll
      for (int n = 0; n < 4; ++n)
        bfr[n] = *reinterpret_cast<const bf16x8*>(&Bs[wc * 64 + n * 16 + (lane & 15)][kk + 8 * (lane >> 4)]);
      #pragma unroll
      for (int m = 0; m < 4; ++m)
        #pragma unroll
        for (int n = 0; n < 4; ++n)
          acc[m][n] = __builtin_amdgcn_mfma_f32_16x16x32_bf16(af[m], bfr[n], acc[m][n], 0, 0, 0);
    }
  }
  const int rb = (lane >> 4) * 4, cb = lane & 15;
  #pragma unroll
  for (int m = 0; m < 4; ++m) {
    #pragma unroll
    for (int n = 0; n < 4; ++n) {
      int gc = Nbase + wc * 64 + n * 16 + cb;
      float bo = bout[gc];
      #pragma unroll
      for (int reg = 0; reg < 4; ++reg) {
        int gr = Mbase + wr * 64 + m * 16 + rb + reg;
        Cmat[(size_t)gr * VOC + gc] = acc[m][n][reg] + bo;
      }
    }
  }
}

// ---------------- in-place log_softmax over V per row ----------------
__global__ __launch_bounds__(256) void logsoftmax_kernel(float* __restrict__ out) {
  __shared__ unsigned short sl[VOC];   // 64000 B
  __shared__ float red[8];
  const size_t base = (size_t)blockIdx.x * VOC;
  const int tid = threadIdx.x;
  float lmax = -1e30f;
  for (int i = tid; i < VOC; i += 256) {
    unsigned short ub = f2b(out[base + i]);
    sl[i] = ub;
    lmax = fmaxf(lmax, b2f(ub));
  }
  #pragma unroll
  for (int off = 32; off; off >>= 1) lmax = fmaxf(lmax, __shfl_xor(lmax, off));
  if ((tid & 63) == 0) red[tid >> 6] = lmax;
  __syncthreads();
  const float gmax = fmaxf(fmaxf(red[0], red[1]), fmaxf(red[2], red[3]));
  float lsum = 0.f;
  for (int i = tid; i < VOC; i += 256) lsum += __expf(b2f(sl[i]) - gmax);
  #pragma unroll
  for (int off = 32; off; off >>= 1) lsum += __shfl_xor(lsum, off);
  if ((tid & 63) == 0) red[4 + (tid >> 6)] = lsum;
  __syncthreads();
  const float lz = gmax + logf(red[4] + red[5] + red[6] + red[7]);
  for (int i = tid; i < VOC; i += 256) out[base + i] = b2f(sl[i]) - lz;
}

extern "C" void kernel_launch(void* const* d_in, const int* in_sizes, int n_in,
                              void* d_out, int out_size, void* d_ws, size_t ws_size,
                              hipStream_t stream) {
  const int*   tok  = (const int*)d_in[0];
  const float* emb  = (const float*)d_in[1];
  const float* Wih1 = (const float*)d_in[2];
  const float* Whh1 = (const float*)d_in[3];
  const float* bih1 = (const float*)d_in[4];
  const float* bhh1 = (const float*)d_in[5];
  const float* U1   = (const float*)d_in[6];
  const float* V1   = (const float*)d_in[7];
  const float* bm1  = (const float*)d_in[8];
  const float* Wih2 = (const float*)d_in[9];
  const float* Whh2 = (const float*)d_in[10];
  const float* bih2 = (const float*)d_in[11];
  const float* bhh2 = (const float*)d_in[12];
  const float* U2   = (const float*)d_in[13];
  const float* V2   = (const float*)d_in[14];
  const float* bm2  = (const float*)d_in[15];
  const float* Wout = (const float*)d_in[16];
  const float* bout = (const float*)d_in[17];
  float* out = (float*)d_out;
  char* ws = (char*)d_ws;

  // workspace layout (bytes)
  float* h1  = (float*)(ws + 0);
  float* c1  = (float*)(ws + 65536);
  float* h2  = (float*)(ws + 131072);
  float* c2  = (float*)(ws + 196608);
  float* x1  = (float*)(ws + 262144);
  float* h1m = (float*)(ws + 327680);
  float* x2  = (float*)(ws + 393216);
  float* h2m = (float*)(ws + 458752);
  unsigned short* hsb  = (unsigned short*)(ws + 524288);   // [4096][512] bf16
  unsigned short* Ut1  = (unsigned short*)(ws + 4718592);
  unsigned short* V1b  = (unsigned short*)(ws + 5179392);
  unsigned short* Ut2  = (unsigned short*)(ws + 5640192);
  unsigned short* V2b  = (unsigned short*)(ws + 6100992);

  hipMemsetAsync(d_ws, 0, 262144, stream);  // zero h1,c1,h2,c2

  cvt_transposeU<<<5 * KR, 512, 0, stream>>>(U1, Ut1);
  cvt_transposeU<<<5 * KR, 512, 0, stream>>>(U2, Ut2);
  cvt_bf16<<<900, 256, 0, stream>>>(V1, V1b, 5 * KR * Hdim);
  cvt_bf16<<<900, 256, 0, stream>>>(V2, V2b, 5 * KR * Hdim);

  for (int t = 0; t < SEQ; ++t) {
    mog_kernel<<<BATCH, 256, 0, stream>>>(emb, tok, t, nullptr, h1, Ut1, V1b, bm1, x1, h1m);
    lstm_kernel<<<256, 256, 0, stream>>>(x1, h1m, c1, h1, Wih1, Whh1, bih1, bhh1, nullptr, t);
    mog_kernel<<<BATCH, 256, 0, stream>>>(nullptr, nullptr, t, h1, h2, Ut2, V2b, bm2, x2, h2m);
    lstm_kernel<<<256, 256, 0, stream>>>(x2, h2m, c2, h2, Wih2, Whh2, bih2, bhh2, hsb, t);
  }

  gemm_out<<<32 * (VOC / 128), 256, 0, stream>>>(hsb, Wout, bout, out);
  logsoftmax_kernel<<<BATCH * SEQ, 256, 0, stream>>>(out);
}

// Round 2
// 8495.927 us; speedup vs baseline: 1.9556x; 1.9556x over previous
//
#include <hip/hip_runtime.h>
#include <hip/hip_bf16.h>

#define Hdim 512
#define KR   90
#define KRP  96
#define BATCH 32
#define SEQ  128
#define VOC  32000
#define NBLK 64

typedef __attribute__((ext_vector_type(8))) short bf16x8;
typedef __attribute__((ext_vector_type(4))) float f32x4;
typedef __attribute__((ext_vector_type(8))) unsigned short u16x8;

__device__ __forceinline__ float b2f(unsigned short u) {
  union { unsigned int i; float f; } w; w.i = ((unsigned int)u) << 16; return w.f;
}
__device__ __forceinline__ unsigned short f2b(float f) {
  __hip_bfloat16 h = __float2bfloat16(f);
  return *reinterpret_cast<unsigned short*>(&h);
}
__device__ __forceinline__ float sigm(float x) { return 1.f / (1.f + expf(-x)); }

// ---------------- setup: weight conversion ----------------
// U: [5][512][90] fp32 -> Ut: [5][90][512] bf16
__global__ __launch_bounds__(512) void cvt_transposeU(const float* __restrict__ U,
                                                      unsigned short* __restrict__ Ut) {
  int i = blockIdx.x / KR, j = blockIdx.x % KR;
  int k = threadIdx.x;
  Ut[((size_t)i * KR + j) * Hdim + k] = f2b(U[((size_t)i * Hdim + k) * KR + j]);
}

// V: [5][90][512] fp32 -> Vt: [5][512][96] bf16 (pad j 90..95 with 0)
__global__ __launch_bounds__(128) void cvt_transposeV(const float* __restrict__ V,
                                                      unsigned short* __restrict__ Vt) {
  int i = blockIdx.x / Hdim, c = blockIdx.x % Hdim;
  int j = threadIdx.x;
  if (j < KRP) {
    float v = (j < KR) ? V[((size_t)i * KR + j) * Hdim + c] : 0.f;
    Vt[((size_t)i * Hdim + c) * KRP + j] = f2b(v);
  }
}

// Wcat row r = [Wih[r] | Whh[r]] in bf16, [2048][1024]
__global__ __launch_bounds__(512) void cvt_wcat(const float* __restrict__ Wih,
                                                const float* __restrict__ Whh,
                                                unsigned short* __restrict__ Wcat) {
  int r = blockIdx.x, c = threadIdx.x;
  Wcat[(size_t)r * 1024 + c]       = f2b(Wih[(size_t)r * Hdim + c]);
  Wcat[(size_t)r * 1024 + 512 + c] = f2b(Whh[(size_t)r * Hdim + c]);
}

__global__ __launch_bounds__(256) void add_bias(const float* __restrict__ a,
                                                const float* __restrict__ b,
                                                float* __restrict__ o) {
  int i = blockIdx.x * 256 + threadIdx.x;
  if (i < 2048) o[i] = a[i] + b[i];
}

// ---------------- persistent recurrence kernel ----------------
struct Smem {
  union {
    struct { float xv[512]; float hv[512]; float tv[96]; } m;
    struct { unsigned short As[32][1032]; float gbuf[2][4][16][16]; } l;
  } u;
};

__device__ __forceinline__ void gbar(unsigned* bar) {
  __syncthreads();
  if (threadIdx.x == 0) {
    __threadfence();  // release: flush this block's data out of the XCD L2
    unsigned g = __hip_atomic_load(&bar[1], __ATOMIC_RELAXED, __HIP_MEMORY_SCOPE_AGENT);
    unsigned a = __hip_atomic_fetch_add(&bar[0], 1u, __ATOMIC_RELAXED, __HIP_MEMORY_SCOPE_AGENT);
    if (a == NBLK - 1) {
      __hip_atomic_store(&bar[0], 0u, __ATOMIC_RELAXED, __HIP_MEMORY_SCOPE_AGENT);
      __hip_atomic_store(&bar[1], g + 1u, __ATOMIC_RELEASE, __HIP_MEMORY_SCOPE_AGENT);
    } else {
      while (__hip_atomic_load(&bar[1], __ATOMIC_RELAXED, __HIP_MEMORY_SCOPE_AGENT) == g) {
        __builtin_amdgcn_s_sleep(4);
      }
    }
    __threadfence();  // acquire: invalidate stale lines before consuming others' data
  }
  __syncthreads();
}

__global__ __launch_bounds__(512, 1) void recurrence(
    const int* __restrict__ tok, const float* __restrict__ emb,
    const unsigned short* __restrict__ Ut,    // [2][5][90][512]
    const unsigned short* __restrict__ Vt,    // [2][5][512][96]
    const float* __restrict__ bm1, const float* __restrict__ bm2,
    const unsigned short* __restrict__ Wcat,  // [2][2048][1024]
    const float* __restrict__ bsum,           // [2][2048]
    float* __restrict__ h1, float* __restrict__ c1,
    float* __restrict__ h2, float* __restrict__ c2,
    unsigned short* __restrict__ act1, unsigned short* __restrict__ act2,
    unsigned short* __restrict__ hsb,
    unsigned* __restrict__ bar)
{
  __shared__ Smem sm;
  const int bid = blockIdx.x, tid = threadIdx.x;
  const int layer = bid >> 5;   // 0: layer1 (step i), 1: layer2 (step i-1)
  const int sub = bid & 31;     // mog: batch row; lstm: 16-col slice

  const unsigned short* UtL = Ut + (size_t)layer * 5 * KR * Hdim;
  const unsigned short* VtL = Vt + (size_t)layer * 5 * Hdim * KRP;
  const float* bm = layer ? bm2 : bm1;
  const unsigned short* W = Wcat + (size_t)layer * 2048 * 1024;
  const float* bs = bsum + layer * 2048;
  float* cS = layer ? c2 : c1;
  float* hS = layer ? h2 : h1;
  unsigned short* act = layer ? act2 : act1;

  for (int i = 0; i <= SEQ; ++i) {
    const int t = layer ? (i - 1) : i;
    const bool active = layer ? (i >= 1) : (i < SEQ);

    // ---------- phase A: mogrifier (row = sub) ----------
    if (active) {
      const float* xsrc = layer ? (h1 + (size_t)sub * Hdim)
                                : (emb + (size_t)tok[sub * SEQ + t] * Hdim);
      const float* hst = hS + (size_t)sub * Hdim;
      sm.u.m.xv[tid] = xsrc[tid];
      sm.u.m.hv[tid] = hst[tid];
      if (tid < 6) sm.u.m.tv[KR + tid] = 0.f;
      __syncthreads();
      for (int it = 0; it < 5; ++it) {
        const float* src = (it & 1) ? sm.u.m.xv : sm.u.m.hv;
        float* dst = (it & 1) ? sm.u.m.hv : sm.u.m.xv;
        if (tid < 360) {
          int j = tid >> 2, q = tid & 3;
          const unsigned short* urow = UtL + ((size_t)it * KR + j) * Hdim + q * 128;
          const float* s = src + q * 128;
          float a0 = 0.f, a1 = 0.f, a2 = 0.f, a3 = 0.f;
          #pragma unroll
          for (int k = 0; k < 128; k += 8) {
            u16x8 u = *reinterpret_cast<const u16x8*>(urow + k);
            a0 += s[k + 0] * b2f(u[0]); a1 += s[k + 1] * b2f(u[1]);
            a2 += s[k + 2] * b2f(u[2]); a3 += s[k + 3] * b2f(u[3]);
            a0 += s[k + 4] * b2f(u[4]); a1 += s[k + 5] * b2f(u[5]);
            a2 += s[k + 6] * b2f(u[6]); a3 += s[k + 7] * b2f(u[7]);
          }
          float v = (a0 + a1) + (a2 + a3);
          v += __shfl_xor(v, 1);
          v += __shfl_xor(v, 2);
          if (q == 0) sm.u.m.tv[j] = v;
        }
        __syncthreads();
        {
          float acc = bm[it * Hdim + tid];
          const unsigned short* vrow = VtL + ((size_t)it * Hdim + tid) * KRP;
          #pragma unroll
          for (int j = 0; j < KRP; j += 8) {
            u16x8 v8 = *reinterpret_cast<const u16x8*>(vrow + j);
            acc += sm.u.m.tv[j + 0] * b2f(v8[0]) + sm.u.m.tv[j + 1] * b2f(v8[1])
                 + sm.u.m.tv[j + 2] * b2f(v8[2]) + sm.u.m.tv[j + 3] * b2f(v8[3])
                 + sm.u.m.tv[j + 4] * b2f(v8[4]) + sm.u.m.tv[j + 5] * b2f(v8[5])
                 + sm.u.m.tv[j + 6] * b2f(v8[6]) + sm.u.m.tv[j + 7] * b2f(v8[7]);
          }
          dst[tid] *= 2.f * sigm(acc);
        }
        __syncthreads();
      }
      unsigned short* arow = act + (size_t)sub * 1024;
      arow[tid]       = f2b(sm.u.m.xv[tid]);
      arow[512 + tid] = f2b(sm.u.m.hv[tid]);
    }
    gbar(bar);

    // ---------- phase B: LSTM (col slice = sub, 16 h-cols x 4 gates) ----------
    if (active) {
      #pragma unroll
      for (int ii = 0; ii < 8; ++ii) {
        int s = tid + 512 * ii;
        int row = s >> 7, c8 = s & 127;
        *reinterpret_cast<u16x8*>(&sm.u.l.As[row][c8 * 8]) =
            *reinterpret_cast<const u16x8*>(act + (size_t)row * 1024 + c8 * 8);
      }
      __syncthreads();
      const int w = tid >> 6, lane = tid & 63;
      const int m = w >> 2, n = w & 3;
      const int koff = 8 * (lane >> 4);
      const unsigned short* wrow =
          W + ((size_t)(n * Hdim + sub * 16 + (lane & 15))) * 1024 + koff;
      const unsigned short* aptr = &sm.u.l.As[m * 16 + (lane & 15)][koff];
      f32x4 acc = {0.f, 0.f, 0.f, 0.f};
      #pragma unroll
      for (int k0 = 0; k0 < 1024; k0 += 32) {
        bf16x8 af = *reinterpret_cast<const bf16x8*>(aptr + k0);
        bf16x8 bf = *reinterpret_cast<const bf16x8*>(wrow + k0);
        acc = __builtin_amdgcn_mfma_f32_16x16x32_bf16(af, bf, acc, 0, 0, 0);
      }
      {
        int col = lane & 15, r0 = (lane >> 4) * 4;
        #pragma unroll
        for (int r = 0; r < 4; ++r) sm.u.l.gbuf[m][n][r0 + r][col] = acc[r];
      }
      __syncthreads();
      {
        int row = tid >> 4, col = tid & 15;
        int mm = row >> 4, lr = row & 15;
        int gc = sub * 16 + col;
        float gi = sm.u.l.gbuf[mm][0][lr][col] + bs[gc];
        float gf = sm.u.l.gbuf[mm][1][lr][col] + bs[512 + gc];
        float gg = sm.u.l.gbuf[mm][2][lr][col] + bs[1024 + gc];
        float go = sm.u.l.gbuf[mm][3][lr][col] + bs[1536 + gc];
        size_t idx = (size_t)row * Hdim + gc;
        float cn = sigm(gf) * cS[idx] + sigm(gi) * tanhf(gg);
        float hn = sigm(go) * tanhf(cn);
        cS[idx] = cn;
        hS[idx] = hn;
        if (layer) hsb[((size_t)row * SEQ + t) * Hdim + gc] = f2b(hn);
      }
    }
    gbar(bar);
  }
}

// ---------------- output GEMM: logits = hs @ Wout^T + b (verified round 1) ----------------
__global__ __launch_bounds__(256) void gemm_out(
    const unsigned short* __restrict__ A,
    const float* __restrict__ Wout,
    const float* __restrict__ bout,
    float* __restrict__ Cmat)
{
  __shared__ unsigned short As[128][72], Bs[128][72];
  const int Mbase = (blockIdx.x & 31) * 128;
  const int Nbase = (blockIdx.x >> 5) * 128;
  const int tid = threadIdx.x, lane = tid & 63, wid = tid >> 6;
  const int wr = wid >> 1, wc = wid & 1;
  f32x4 acc[4][4];
  #pragma unroll
  for (int m = 0; m < 4; ++m)
    #pragma unroll
    for (int n = 0; n < 4; ++n) acc[m][n] = (f32x4){0.f, 0.f, 0.f, 0.f};

  for (int kt = 0; kt < 8; ++kt) {
    const int k0 = kt * 64;
    __syncthreads();
    #pragma unroll
    for (int i = 0; i < 4; ++i) {
      int s = tid + 256 * i;
      int row = s >> 3, c8 = s & 7;
      u16x8 v = *reinterpret_cast<const u16x8*>(A + ((size_t)(Mbase + row)) * Hdim + k0 + c8 * 8);
      *reinterpret_cast<u16x8*>(&As[row][c8 * 8]) = v;
    }
    #pragma unroll
    for (int i = 0; i < 8; ++i) {
      int s = tid + 256 * i;
      int row = s >> 4, c4 = s & 15;
      float4 v = *reinterpret_cast<const float4*>(Wout + ((size_t)(Nbase + row)) * Hdim + k0 + c4 * 4);
      ushort4 b4;
      b4.x = f2b(v.x); b4.y = f2b(v.y); b4.z = f2b(v.z); b4.w = f2b(v.w);
      *reinterpret_cast<ushort4*>(&Bs[row][c4 * 4]) = b4;
    }
    __syncthreads();
    #pragma unroll
    for (int kk = 0; kk < 64; kk += 32) {
      bf16x8 af[4], bfr[4];
      #pragma unroll
      for (int m = 0; m < 4; ++m)
        af[m] = *reinterpret_cast<const bf16x8*>(&As[wr * 64 + m * 16 + (lane & 15)][kk + 8 * (lane >> 4)]);
      #pragma unroll
      for (int n = 0; n < 4; ++n)
        bfr[n] = *reinterpret_cast<const bf16x8*>(&Bs[wc * 64 + n * 16 + (lane & 15)][kk + 8 * (lane >> 4)]);
      #pragma unroll
      for (int m = 0; m < 4; ++m)
        #pragma unroll
        for (int n = 0; n < 4; ++n)
          acc[m][n] = __builtin_amdgcn_mfma_f32_16x16x32_bf16(af[m], bfr[n], acc[m][n], 0, 0, 0);
    }
  }
  const int rb = (lane >> 4) * 4, cb = lane & 15;
  #pragma unroll
  for (int m = 0; m < 4; ++m) {
    #pragma unroll
    for (int n = 0; n < 4; ++n) {
      int gc = Nbase + wc * 64 + n * 16 + cb;
      float bo = bout[gc];
      #pragma unroll
      for (int reg = 0; reg < 4; ++reg) {
        int gr = Mbase + wr * 64 + m * 16 + rb + reg;
        Cmat[(size_t)gr * VOC + gc] = acc[m][n][reg] + bo;
      }
    }
  }
}

// ---------------- in-place log_softmax over V per row ----------------
__global__ __launch_bounds__(256) void logsoftmax_kernel(float* __restrict__ out) {
  __shared__ unsigned short sl[VOC];
  __shared__ float red[8];
  const size_t base = (size_t)blockIdx.x * VOC;
  const int tid = threadIdx.x;
  float lmax = -1e30f;
  for (int i = tid; i < VOC; i += 256) {
    unsigned short ub = f2b(out[base + i]);
    sl[i] = ub;
    lmax = fmaxf(lmax, b2f(ub));
  }
  #pragma unroll
  for (int off = 32; off; off >>= 1) lmax = fmaxf(lmax, __shfl_xor(lmax, off));
  if ((tid & 63) == 0) red[tid >> 6] = lmax;
  __syncthreads();
  const float gmax = fmaxf(fmaxf(red[0], red[1]), fmaxf(red[2], red[3]));
  float lsum = 0.f;
  for (int i = tid; i < VOC; i += 256) lsum += __expf(b2f(sl[i]) - gmax);
  #pragma unroll
  for (int off = 32; off; off >>= 1) lsum += __shfl_xor(lsum, off);
  if ((tid & 63) == 0) red[4 + (tid >> 6)] = lsum;
  __syncthreads();
  const float lz = gmax + logf(red[4] + red[5] + red[6] + red[7]);
  for (int i = tid; i < VOC; i += 256) out[base + i] = b2f(sl[i]) - lz;
}

extern "C" void kernel_launch(void* const* d_in, const int* in_sizes, int n_in,
                              void* d_out, int out_size, void* d_ws, size_t ws_size,
                              hipStream_t stream) {
  const int*   tok  = (const int*)d_in[0];
  const float* emb  = (const float*)d_in[1];
  const float* Wih1 = (const float*)d_in[2];
  const float* Whh1 = (const float*)d_in[3];
  const float* bih1 = (const float*)d_in[4];
  const float* bhh1 = (const float*)d_in[5];
  const float* U1   = (const float*)d_in[6];
  const float* V1   = (const float*)d_in[7];
  const float* bm1  = (const float*)d_in[8];
  const float* Wih2 = (const float*)d_in[9];
  const float* Whh2 = (const float*)d_in[10];
  const float* bih2 = (const float*)d_in[11];
  const float* bhh2 = (const float*)d_in[12];
  const float* U2   = (const float*)d_in[13];
  const float* V2   = (const float*)d_in[14];
  const float* bm2  = (const float*)d_in[15];
  const float* Wout = (const float*)d_in[16];
  const float* bout = (const float*)d_in[17];
  float* out = (float*)d_out;
  char* ws = (char*)d_ws;

  // workspace layout
  float* h1 = (float*)(ws + 0);
  float* c1 = (float*)(ws + 65536);
  float* h2 = (float*)(ws + 131072);
  float* c2 = (float*)(ws + 196608);
  unsigned* bar = (unsigned*)(ws + 262144);             // 256 B reserved
  unsigned short* act1 = (unsigned short*)(ws + 262400);
  unsigned short* act2 = (unsigned short*)(ws + 327936);
  float* bsum = (float*)(ws + 393472);                  // [2][2048]
  unsigned short* Ut   = (unsigned short*)(ws + 409856);   // [2][5][90][512]
  unsigned short* Vt   = (unsigned short*)(ws + 1331456);  // [2][5][512][96]
  unsigned short* Wcat = (unsigned short*)(ws + 2314496);  // [2][2048][1024]
  unsigned short* hsb  = (unsigned short*)(ws + 10703104); // [32][128][512]

  hipMemsetAsync(d_ws, 0, 262400, stream);  // states + barrier

  cvt_transposeU<<<5 * KR, 512, 0, stream>>>(U1, Ut);
  cvt_transposeU<<<5 * KR, 512, 0, stream>>>(U2, Ut + 5 * KR * Hdim);
  cvt_transposeV<<<5 * Hdim, 128, 0, stream>>>(V1, Vt);
  cvt_transposeV<<<5 * Hdim, 128, 0, stream>>>(V2, Vt + 5 * Hdim * KRP);
  cvt_wcat<<<2048, 512, 0, stream>>>(Wih1, Whh1, Wcat);
  cvt_wcat<<<2048, 512, 0, stream>>>(Wih2, Whh2, Wcat + (size_t)2048 * 1024);
  add_bias<<<8, 256, 0, stream>>>(bih1, bhh1, bsum);
  add_bias<<<8, 256, 0, stream>>>(bih2, bhh2, bsum + 2048);

  recurrence<<<NBLK, 512, 0, stream>>>(tok, emb, Ut, Vt, bm1, bm2, Wcat, bsum,
                                       h1, c1, h2, c2, act1, act2, hsb, bar);

  gemm_out<<<32 * (VOC / 128), 256, 0, stream>>>(hsb, Wout, bout, out);
  logsoftmax_kernel<<<BATCH * SEQ, 256, 0, stream>>>(out);
}

// Round 3
// 7100.464 us; speedup vs baseline: 2.3399x; 1.1965x over previous
//
#include <hip/hip_runtime.h>
#include <hip/hip_bf16.h>

#define Hdim 512
#define KR   90
#define KRP  96
#define BATCH 32
#define SEQ  128
#define VOC  32000
#define NBLK 64

typedef __attribute__((ext_vector_type(8))) short bf16x8;
typedef __attribute__((ext_vector_type(4))) float f32x4;
typedef __attribute__((ext_vector_type(8))) unsigned short u16x8;

__device__ __forceinline__ float b2f(unsigned short u) {
  union { unsigned int i; float f; } w; w.i = ((unsigned int)u) << 16; return w.f;
}
__device__ __forceinline__ unsigned short f2b(float f) {
  __hip_bfloat16 h = __float2bfloat16(f);
  return *reinterpret_cast<unsigned short*>(&h);
}
__device__ __forceinline__ float sigm(float x) { return 1.f / (1.f + expf(-x)); }

// coherent (L2-bypassing) exchange helpers — agent-scope relaxed atomics
__device__ __forceinline__ float ld_cohf(const float* p) {
  return __hip_atomic_load(p, __ATOMIC_RELAXED, __HIP_MEMORY_SCOPE_AGENT);
}
__device__ __forceinline__ void st_cohf(float* p, float v) {
  __hip_atomic_store(p, v, __ATOMIC_RELAXED, __HIP_MEMORY_SCOPE_AGENT);
}
__device__ __forceinline__ unsigned long long ld_cohu64(const unsigned long long* p) {
  return __hip_atomic_load(p, __ATOMIC_RELAXED, __HIP_MEMORY_SCOPE_AGENT);
}
__device__ __forceinline__ void st_cohu32(unsigned* p, unsigned v) {
  __hip_atomic_store(p, v, __ATOMIC_RELAXED, __HIP_MEMORY_SCOPE_AGENT);
}

// ---------------- setup: weight conversion ----------------
__global__ __launch_bounds__(512) void cvt_transposeU(const float* __restrict__ U,
                                                      unsigned short* __restrict__ Ut) {
  int i = blockIdx.x / KR, j = blockIdx.x % KR;
  int k = threadIdx.x;
  Ut[((size_t)i * KR + j) * Hdim + k] = f2b(U[((size_t)i * Hdim + k) * KR + j]);
}

__global__ __launch_bounds__(128) void cvt_transposeV(const float* __restrict__ V,
                                                      unsigned short* __restrict__ Vt) {
  int i = blockIdx.x / Hdim, c = blockIdx.x % Hdim;
  int j = threadIdx.x;
  if (j < KRP) {
    float v = (j < KR) ? V[((size_t)i * KR + j) * Hdim + c] : 0.f;
    Vt[((size_t)i * Hdim + c) * KRP + j] = f2b(v);
  }
}

__global__ __launch_bounds__(512) void cvt_wcat(const float* __restrict__ Wih,
                                                const float* __restrict__ Whh,
                                                unsigned short* __restrict__ Wcat) {
  int r = blockIdx.x, c = threadIdx.x;
  Wcat[(size_t)r * 1024 + c]       = f2b(Wih[(size_t)r * Hdim + c]);
  Wcat[(size_t)r * 1024 + 512 + c] = f2b(Whh[(size_t)r * Hdim + c]);
}

__global__ __launch_bounds__(256) void add_bias(const float* __restrict__ a,
                                                const float* __restrict__ b,
                                                float* __restrict__ o) {
  int i = blockIdx.x * 256 + threadIdx.x;
  if (i < 2048) o[i] = a[i] + b[i];
}

// ---------------- persistent recurrence kernel ----------------
struct Smem {
  union {
    struct { float xv[512]; float hv[512]; float tv[96]; } m;
    struct { unsigned short As[32 * 1024]; float gbuf[2][4][16][17]; } l;
  } u;
};

// fence-free grid barrier: u64 = {gen:32 | count:32}, relaxed agent atomics only.
// store->signal ordering: each wave drains vmcnt before s_barrier (explicit + compiler).
__device__ __forceinline__ void gbar(unsigned long long* bar) {
  asm volatile("s_waitcnt vmcnt(0)" ::: "memory");
  __syncthreads();
  if (threadIdx.x == 0) {
    unsigned long long old =
        __hip_atomic_fetch_add(bar, 1ull, __ATOMIC_RELAXED, __HIP_MEMORY_SCOPE_AGENT);
    unsigned g = (unsigned)(old >> 32);
    if ((unsigned)(old & 0xffffffffu) == NBLK - 1) {
      // single store atomically resets count and bumps generation
      __hip_atomic_store(bar, ((unsigned long long)(g + 1)) << 32,
                         __ATOMIC_RELAXED, __HIP_MEMORY_SCOPE_AGENT);
    } else {
      while ((unsigned)(__hip_atomic_load(bar, __ATOMIC_RELAXED,
                                          __HIP_MEMORY_SCOPE_AGENT) >> 32) == g)
        __builtin_amdgcn_s_sleep(1);
    }
  }
  __syncthreads();
}

__global__ __launch_bounds__(512, 1) void recurrence(
    const int* __restrict__ tok, const float* __restrict__ emb,
    const unsigned short* __restrict__ Ut,    // [2][5][90][512]
    const unsigned short* __restrict__ Vt,    // [2][5][512][96]
    const float* __restrict__ bm1, const float* __restrict__ bm2,
    const unsigned short* __restrict__ Wcat,  // [2][2048][1024]
    const float* __restrict__ bsum,           // [2][2048]
    float* __restrict__ h1, float* __restrict__ c1,
    float* __restrict__ h2, float* __restrict__ c2,
    unsigned short* __restrict__ act1, unsigned short* __restrict__ act2,
    unsigned short* __restrict__ hsb,
    unsigned long long* __restrict__ bar)
{
  __shared__ Smem sm;
  const int bid = blockIdx.x, tid = threadIdx.x;
  const int layer = bid >> 5;
  const int sub = bid & 31;

  const unsigned short* UtL = Ut + (size_t)layer * 5 * KR * Hdim;
  const unsigned short* VtL = Vt + (size_t)layer * 5 * Hdim * KRP;
  const float* bm = layer ? bm2 : bm1;
  const unsigned short* W = Wcat + (size_t)layer * 2048 * 1024;
  const float* bs = bsum + layer * 2048;
  float* cS = layer ? c2 : c1;
  float* hS = layer ? h2 : h1;
  unsigned short* act = layer ? act2 : act1;

  for (int i = 0; i <= SEQ; ++i) {
    const int t = layer ? (i - 1) : i;
    const bool active = layer ? (i >= 1) : (i < SEQ);

    // ---------- phase A: mogrifier (row = sub) ----------
    if (active) {
      float xval;
      if (layer) xval = ld_cohf(h1 + (size_t)sub * Hdim + tid);
      else       xval = emb[(size_t)tok[sub * SEQ + t] * Hdim + tid];  // cached (read-only)
      float hval = ld_cohf(hS + (size_t)sub * Hdim + tid);
      sm.u.m.xv[tid] = xval;
      sm.u.m.hv[tid] = hval;
      if (tid < 6) sm.u.m.tv[KR + tid] = 0.f;
      __syncthreads();
      for (int it = 0; it < 5; ++it) {
        const float* src = (it & 1) ? sm.u.m.xv : sm.u.m.hv;
        float* dst = (it & 1) ? sm.u.m.hv : sm.u.m.xv;
        // stage 1: tv[j] = sum_k src[k]*U[k][j]; thread (j,q) covers k = q*8 + 32m
        if (tid < 360) {
          int j = tid >> 2, q = tid & 3;
          const unsigned short* urow = UtL + ((size_t)it * KR + j) * Hdim + q * 8;
          const float* s = src + q * 8;
          float a0 = 0.f, a1 = 0.f, a2 = 0.f, a3 = 0.f;
          #pragma unroll
          for (int m = 0; m < 16; ++m) {
            u16x8 u = *reinterpret_cast<const u16x8*>(urow + 32 * m);
            const float* sp = s + 32 * m;
            a0 += sp[0] * b2f(u[0]); a1 += sp[1] * b2f(u[1]);
            a2 += sp[2] * b2f(u[2]); a3 += sp[3] * b2f(u[3]);
            a0 += sp[4] * b2f(u[4]); a1 += sp[5] * b2f(u[5]);
            a2 += sp[6] * b2f(u[6]); a3 += sp[7] * b2f(u[7]);
          }
          float v = (a0 + a1) + (a2 + a3);
          v += __shfl_xor(v, 1);
          v += __shfl_xor(v, 2);
          if (q == 0) sm.u.m.tv[j] = v;
        }
        __syncthreads();
        // stage 2
        {
          float acc = bm[it * Hdim + tid];
          const unsigned short* vrow = VtL + ((size_t)it * Hdim + tid) * KRP;
          #pragma unroll
          for (int j = 0; j < KRP; j += 8) {
            u16x8 v8 = *reinterpret_cast<const u16x8*>(vrow + j);
            acc += sm.u.m.tv[j + 0] * b2f(v8[0]) + sm.u.m.tv[j + 1] * b2f(v8[1])
                 + sm.u.m.tv[j + 2] * b2f(v8[2]) + sm.u.m.tv[j + 3] * b2f(v8[3])
                 + sm.u.m.tv[j + 4] * b2f(v8[4]) + sm.u.m.tv[j + 5] * b2f(v8[5])
                 + sm.u.m.tv[j + 6] * b2f(v8[6]) + sm.u.m.tv[j + 7] * b2f(v8[7]);
          }
          dst[tid] *= 2.f * sigm(acc);
        }
        __syncthreads();
      }
      // write act = [x(512) | h(512)] bf16, coherent u32 pairs
      unsigned* arow = reinterpret_cast<unsigned*>(act + (size_t)sub * 1024);
      if (tid < 256) {
        unsigned v = (unsigned)f2b(sm.u.m.xv[2 * tid]) |
                     ((unsigned)f2b(sm.u.m.xv[2 * tid + 1]) << 16);
        st_cohu32(arow + tid, v);
      } else {
        int t2 = tid - 256;
        unsigned v = (unsigned)f2b(sm.u.m.hv[2 * t2]) |
                     ((unsigned)f2b(sm.u.m.hv[2 * t2 + 1]) << 16);
        st_cohu32(arow + 256 + t2, v);
      }
    }
    gbar(bar);

    // ---------- phase B: LSTM (col slice = sub) ----------
    if (active) {
      // stage act [32][1024] bf16 -> LDS with XOR swizzle (byte ^= (row&7)<<4)
      const unsigned long long* asrc = reinterpret_cast<const unsigned long long*>(act);
      char* As = reinterpret_cast<char*>(sm.u.l.As);
      #pragma unroll
      for (int ii = 0; ii < 16; ++ii) {
        int s = tid + 512 * ii;          // u64 index, 8192 total
        int row = s >> 8, c = s & 255;
        unsigned long long v = ld_cohu64(asrc + s);
        *reinterpret_cast<unsigned long long*>(
            As + ((row * 2048 + c * 8) ^ ((row & 7) << 4))) = v;
      }
      __syncthreads();
      const int w = tid >> 6, lane = tid & 63;
      const int m = w >> 2, n = w & 3;
      const int r15 = lane & 15, g = lane >> 4;
      const int arow_ = m * 16 + r15;
      const int abase = arow_ * 2048 + g * 16;
      const int aswz = (arow_ & 7) << 4;
      const unsigned short* wrow =
          W + ((size_t)(n * Hdim + sub * 16 + r15)) * 1024 + 8 * g;
      f32x4 acc = {0.f, 0.f, 0.f, 0.f};
      #pragma unroll
      for (int k0 = 0; k0 < 1024; k0 += 32) {
        bf16x8 af = *reinterpret_cast<const bf16x8*>(As + ((abase + 2 * k0) ^ aswz));
        bf16x8 bf = *reinterpret_cast<const bf16x8*>(wrow + k0);
        acc = __builtin_amdgcn_mfma_f32_16x16x32_bf16(af, bf, acc, 0, 0, 0);
      }
      {
        int r0 = g * 4;
        #pragma unroll
        for (int r = 0; r < 4; ++r) sm.u.l.gbuf[m][n][r0 + r][r15] = acc[r];
      }
      __syncthreads();
      {
        int row = tid >> 4, col = tid & 15;
        int mm = row >> 4, lr = row & 15;
        int gc = sub * 16 + col;
        float gi = sm.u.l.gbuf[mm][0][lr][col] + bs[gc];
        float gf = sm.u.l.gbuf[mm][1][lr][col] + bs[512 + gc];
        float gg = sm.u.l.gbuf[mm][2][lr][col] + bs[1024 + gc];
        float go = sm.u.l.gbuf[mm][3][lr][col] + bs[1536 + gc];
        size_t idx = (size_t)row * Hdim + gc;
        float cn = sigm(gf) * cS[idx] + sigm(gi) * tanhf(gg);   // c: block-private, cached
        float hn = sigm(go) * tanhf(cn);
        cS[idx] = cn;
        st_cohf(hS + idx, hn);                                   // h: cross-block, coherent
        if (layer) hsb[((size_t)row * SEQ + t) * Hdim + gc] = f2b(hn);
      }
    }
    gbar(bar);
  }
}

// ---------------- output GEMM: logits = hs @ Wout^T + b ----------------
__global__ __launch_bounds__(256) void gemm_out(
    const unsigned short* __restrict__ A,
    const float* __restrict__ Wout,
    const float* __restrict__ bout,
    float* __restrict__ Cmat)
{
  __shared__ unsigned short As[128][72], Bs[128][72];
  const int Mbase = (blockIdx.x & 31) * 128;
  const int Nbase = (blockIdx.x >> 5) * 128;
  const int tid = threadIdx.x, lane = tid & 63, wid = tid >> 6;
  const int wr = wid >> 1, wc = wid & 1;
  f32x4 acc[4][4];
  #pragma unroll
  for (int m = 0; m < 4; ++m)
    #pragma unroll
    for (int n = 0; n < 4; ++n) acc[m][n] = (f32x4){0.f, 0.f, 0.f, 0.f};

  for (int kt = 0; kt < 8; ++kt) {
    const int k0 = kt * 64;
    __syncthreads();
    #pragma unroll
    for (int i = 0; i < 4; ++i) {
      int s = tid + 256 * i;
      int row = s >> 3, c8 = s & 7;
      u16x8 v = *reinterpret_cast<const u16x8*>(A + ((size_t)(Mbase + row)) * Hdim + k0 + c8 * 8);
      *reinterpret_cast<u16x8*>(&As[row][c8 * 8]) = v;
    }
    #pragma unroll
    for (int i = 0; i < 8; ++i) {
      int s = tid + 256 * i;
      int row = s >> 4, c4 = s & 15;
      float4 v = *reinterpret_cast<const float4*>(Wout + ((size_t)(Nbase + row)) * Hdim + k0 + c4 * 4);
      ushort4 b4;
      b4.x = f2b(v.x); b4.y = f2b(v.y); b4.z = f2b(v.z); b4.w = f2b(v.w);
      *reinterpret_cast<ushort4*>(&Bs[row][c4 * 4]) = b4;
    }
    __syncthreads();
    #pragma unroll
    for (int kk = 0; kk < 64; kk += 32) {
      bf16x8 af[4], bfr[4];
      #pragma unroll
      for (int m = 0; m < 4; ++m)
        af[m] = *reinterpret_cast<const bf16x8*>(&As[wr * 64 + m * 16 + (lane & 15)][kk + 8 * (lane >> 4)]);
      #pragma unroll
      for (int n = 0; n < 4; ++n)
        bfr[n] = *reinterpret_cast<const bf16x8*>(&Bs[wc * 64 + n * 16 + (lane & 15)][kk + 8 * (lane >> 4)]);
      #pragma unroll
      for (int m = 0; m < 4; ++m)
        #pragma unroll
        for (int n = 0; n < 4; ++n)
          acc[m][n] = __builtin_amdgcn_mfma_f32_16x16x32_bf16(af[m], bfr[n], acc[m][n], 0, 0, 0);
    }
  }
  const int rb = (lane >> 4) * 4, cb = lane & 15;
  #pragma unroll
  for (int m = 0; m < 4; ++m) {
    #pragma unroll
    for (int n = 0; n < 4; ++n) {
      int gc = Nbase + wc * 64 + n * 16 + cb;
      float bo = bout[gc];
      #pragma unroll
      for (int reg = 0; reg < 4; ++reg) {
        int gr = Mbase + wr * 64 + m * 16 + rb + reg;
        Cmat[(size_t)gr * VOC + gc] = acc[m][n][reg] + bo;
      }
    }
  }
}

// ---------------- in-place log_softmax over V per row ----------------
__global__ __launch_bounds__(256) void logsoftmax_kernel(float* __restrict__ out) {
  __shared__ unsigned short sl[VOC];
  __shared__ float red[8];
  const size_t base = (size_t)blockIdx.x * VOC;
  const int tid = threadIdx.x;
  float lmax = -1e30f;
  for (int i = tid; i < VOC; i += 256) {
    unsigned short ub = f2b(out[base + i]);
    sl[i] = ub;
    lmax = fmaxf(lmax, b2f(ub));
  }
  #pragma unroll
  for (int off = 32; off; off >>= 1) lmax = fmaxf(lmax, __shfl_xor(lmax, off));
  if ((tid & 63) == 0) red[tid >> 6] = lmax;
  __syncthreads();
  const float gmax = fmaxf(fmaxf(red[0], red[1]), fmaxf(red[2], red[3]));
  float lsum = 0.f;
  for (int i = tid; i < VOC; i += 256) lsum += __expf(b2f(sl[i]) - gmax);
  #pragma unroll
  for (int off = 32; off; off >>= 1) lsum += __shfl_xor(lsum, off);
  if ((tid & 63) == 0) red[4 + (tid >> 6)] = lsum;
  __syncthreads();
  const float lz = gmax + logf(red[4] + red[5] + red[6] + red[7]);
  for (int i = tid; i < VOC; i += 256) out[base + i] = b2f(sl[i]) - lz;
}

extern "C" void kernel_launch(void* const* d_in, const int* in_sizes, int n_in,
                              void* d_out, int out_size, void* d_ws, size_t ws_size,
                              hipStream_t stream) {
  const int*   tok  = (const int*)d_in[0];
  const float* emb  = (const float*)d_in[1];
  const float* Wih1 = (const float*)d_in[2];
  const float* Whh1 = (const float*)d_in[3];
  const float* bih1 = (const float*)d_in[4];
  const float* bhh1 = (const float*)d_in[5];
  const float* U1   = (const float*)d_in[6];
  const float* V1   = (const float*)d_in[7];
  const float* bm1  = (const float*)d_in[8];
  const float* Wih2 = (const float*)d_in[9];
  const float* Whh2 = (const float*)d_in[10];
  const float* bih2 = (const float*)d_in[11];
  const float* bhh2 = (const float*)d_in[12];
  const float* U2   = (const float*)d_in[13];
  const float* V2   = (const float*)d_in[14];
  const float* bm2  = (const float*)d_in[15];
  const float* Wout = (const float*)d_in[16];
  const float* bout = (const float*)d_in[17];
  float* out = (float*)d_out;
  char* ws = (char*)d_ws;

  // workspace layout
  float* h1 = (float*)(ws + 0);
  float* c1 = (float*)(ws + 65536);
  float* h2 = (float*)(ws + 131072);
  float* c2 = (float*)(ws + 196608);
  unsigned long long* bar = (unsigned long long*)(ws + 262144);  // 256 B reserved
  unsigned short* act1 = (unsigned short*)(ws + 262400);
  unsigned short* act2 = (unsigned short*)(ws + 327936);
  float* bsum = (float*)(ws + 393472);                     // [2][2048]
  unsigned short* Ut   = (unsigned short*)(ws + 409856);   // [2][5][90][512]
  unsigned short* Vt   = (unsigned short*)(ws + 1331456);  // [2][5][512][96]
  unsigned short* Wcat = (unsigned short*)(ws + 2314496);  // [2][2048][1024]
  unsigned short* hsb  = (unsigned short*)(ws + 10703104); // [32][128][512]

  hipMemsetAsync(d_ws, 0, 262400, stream);  // states + barrier

  cvt_transposeU<<<5 * KR, 512, 0, stream>>>(U1, Ut);
  cvt_transposeU<<<5 * KR, 512, 0, stream>>>(U2, Ut + 5 * KR * Hdim);
  cvt_transposeV<<<5 * Hdim, 128, 0, stream>>>(V1, Vt);
  cvt_transposeV<<<5 * Hdim, 128, 0, stream>>>(V2, Vt + 5 * Hdim * KRP);
  cvt_wcat<<<2048, 512, 0, stream>>>(Wih1, Whh1, Wcat);
  cvt_wcat<<<2048, 512, 0, stream>>>(Wih2, Whh2, Wcat + (size_t)2048 * 1024);
  add_bias<<<8, 256, 0, stream>>>(bih1, bhh1, bsum);
  add_bias<<<8, 256, 0, stream>>>(bih2, bhh2, bsum + 2048);

  recurrence<<<NBLK, 512, 0, stream>>>(tok, emb, Ut, Vt, bm1, bm2, Wcat, bsum,
                                       h1, c1, h2, c2, act1, act2, hsb, bar);

  gemm_out<<<32 * (VOC / 128), 256, 0, stream>>>(hsb, Wout, bout, out);
  logsoftmax_kernel<<<BATCH * SEQ, 256, 0, stream>>>(out);
}

// Round 4
// 5523.574 us; speedup vs baseline: 3.0079x; 1.2855x over previous
//
#include <hip/hip_runtime.h>
#include <hip/hip_bf16.h>

#define Hdim 512
#define KR   90
#define KRP  96
#define BATCH 32
#define SEQ  128
#define VOC  32000
#define NBLK 64
#define NTHR 1024

typedef __attribute__((ext_vector_type(8))) short bf16x8;
typedef __attribute__((ext_vector_type(4))) float f32x4;
typedef __attribute__((ext_vector_type(8))) unsigned short u16x8;

__device__ __forceinline__ float b2f(unsigned short u) {
  union { unsigned int i; float f; } w; w.i = ((unsigned int)u) << 16; return w.f;
}
__device__ __forceinline__ unsigned short f2b(float f) {
  __hip_bfloat16 h = __float2bfloat16(f);
  return *reinterpret_cast<unsigned short*>(&h);
}
__device__ __forceinline__ float sigm(float x) { return 1.f / (1.f + expf(-x)); }

// coherent (L2-bypassing) exchange helpers — agent-scope relaxed atomics
__device__ __forceinline__ float ld_cohf(const float* p) {
  return __hip_atomic_load(p, __ATOMIC_RELAXED, __HIP_MEMORY_SCOPE_AGENT);
}
__device__ __forceinline__ void st_cohf(float* p, float v) {
  __hip_atomic_store(p, v, __ATOMIC_RELAXED, __HIP_MEMORY_SCOPE_AGENT);
}
__device__ __forceinline__ unsigned long long ld_cohu64(const unsigned long long* p) {
  return __hip_atomic_load(p, __ATOMIC_RELAXED, __HIP_MEMORY_SCOPE_AGENT);
}
__device__ __forceinline__ void st_cohu32(unsigned* p, unsigned v) {
  __hip_atomic_store(p, v, __ATOMIC_RELAXED, __HIP_MEMORY_SCOPE_AGENT);
}

// ---------------- setup: weight conversion ----------------
__global__ __launch_bounds__(512) void cvt_transposeU(const float* __restrict__ U,
                                                      unsigned short* __restrict__ Ut) {
  int i = blockIdx.x / KR, j = blockIdx.x % KR;
  int k = threadIdx.x;
  Ut[((size_t)i * KR + j) * Hdim + k] = f2b(U[((size_t)i * Hdim + k) * KR + j]);
}

// V: [5][90][512] fp32 -> Vt: [5][12][512][8] bf16 (j-tiled: coalesced across col lanes)
__global__ __launch_bounds__(128) void cvt_transposeV(const float* __restrict__ V,
                                                      unsigned short* __restrict__ Vt) {
  int i = blockIdx.x / Hdim, c = blockIdx.x % Hdim;
  int j = threadIdx.x;
  if (j < KRP) {
    float v = (j < KR) ? V[((size_t)i * KR + j) * Hdim + c] : 0.f;
    int jt = j >> 3, jj = j & 7;
    Vt[(((size_t)i * 12 + jt) * Hdim + c) * 8 + jj] = f2b(v);
  }
}

__global__ __launch_bounds__(512) void cvt_wcat(const float* __restrict__ Wih,
                                                const float* __restrict__ Whh,
                                                unsigned short* __restrict__ Wcat) {
  int r = blockIdx.x, c = threadIdx.x;
  Wcat[(size_t)r * 1024 + c]       = f2b(Wih[(size_t)r * Hdim + c]);
  Wcat[(size_t)r * 1024 + 512 + c] = f2b(Whh[(size_t)r * Hdim + c]);
}

__global__ __launch_bounds__(256) void add_bias(const float* __restrict__ a,
                                                const float* __restrict__ b,
                                                float* __restrict__ o) {
  int i = blockIdx.x * 256 + threadIdx.x;
  if (i < 2048) o[i] = a[i] + b[i];
}

// ---------------- persistent recurrence kernel ----------------
struct Smem {
  union {
    struct { float xv[512]; float hv[512]; float tv[96]; float tp2[2][512]; } m;
    struct { unsigned short As[32 * 1024]; float gbuf[2][2][4][16][17]; } l;
  } u;
};

// fence-free grid barrier: u64 = {gen:32 | count:32}, relaxed agent atomics only.
__device__ __forceinline__ void gbar(unsigned long long* bar) {
  asm volatile("s_waitcnt vmcnt(0)" ::: "memory");
  __syncthreads();
  if (threadIdx.x == 0) {
    unsigned long long old =
        __hip_atomic_fetch_add(bar, 1ull, __ATOMIC_RELAXED, __HIP_MEMORY_SCOPE_AGENT);
    unsigned g = (unsigned)(old >> 32);
    if ((unsigned)(old & 0xffffffffu) == NBLK - 1) {
      __hip_atomic_store(bar, ((unsigned long long)(g + 1)) << 32,
                         __ATOMIC_RELAXED, __HIP_MEMORY_SCOPE_AGENT);
    } else {
      while ((unsigned)(__hip_atomic_load(bar, __ATOMIC_RELAXED,
                                          __HIP_MEMORY_SCOPE_AGENT) >> 32) == g)
        __builtin_amdgcn_s_sleep(1);
    }
  }
  __syncthreads();
}

__global__ __launch_bounds__(NTHR, 1) void recurrence(
    const int* __restrict__ tok, const float* __restrict__ emb,
    const unsigned short* __restrict__ Ut,    // [2][5][90][512]
    const unsigned short* __restrict__ Vt,    // [2][5][12][512][8]
    const float* __restrict__ bm1, const float* __restrict__ bm2,
    const unsigned short* __restrict__ Wcat,  // [2][2048][1024]
    const float* __restrict__ bsum,           // [2][2048]
    float* __restrict__ h1, float* __restrict__ c1,
    float* __restrict__ h2, float* __restrict__ c2,
    unsigned short* __restrict__ act1, unsigned short* __restrict__ act2,
    unsigned short* __restrict__ hsb,
    unsigned long long* __restrict__ bar)
{
  __shared__ Smem sm;
  const int bid = blockIdx.x, tid = threadIdx.x;
  const int layer = bid >> 5;
  const int sub = bid & 31;

  const unsigned short* UtL = Ut + (size_t)layer * 5 * KR * Hdim;
  const unsigned short* VtL = Vt + (size_t)layer * 5 * 12 * Hdim * 8;
  const float* bm = layer ? bm2 : bm1;
  const unsigned short* W = Wcat + (size_t)layer * 2048 * 1024;
  const float* bs = bsum + layer * 2048;
  float* cS = layer ? c2 : c1;
  float* hS = layer ? h2 : h1;
  unsigned short* act = layer ? act2 : act1;

  for (int i = 0; i <= SEQ; ++i) {
    const int t = layer ? (i - 1) : i;
    const bool active = layer ? (i >= 1) : (i < SEQ);

    // ---------- phase A: mogrifier (row = sub) ----------
    if (active) {
      if (tid < 256) {
        // x float-pair tid
        if (layer) {
          unsigned long long v =
              ld_cohu64((const unsigned long long*)(h1 + (size_t)sub * Hdim) + tid);
          float2 f; __builtin_memcpy(&f, &v, 8);
          sm.u.m.xv[2 * tid] = f.x; sm.u.m.xv[2 * tid + 1] = f.y;
        } else {
          float2 f = *reinterpret_cast<const float2*>(
              emb + (size_t)tok[sub * SEQ + t] * Hdim + 2 * tid);
          sm.u.m.xv[2 * tid] = f.x; sm.u.m.xv[2 * tid + 1] = f.y;
        }
      } else if (tid < 512) {
        int p = tid - 256;
        unsigned long long v =
            ld_cohu64((const unsigned long long*)(hS + (size_t)sub * Hdim) + p);
        float2 f; __builtin_memcpy(&f, &v, 8);
        sm.u.m.hv[2 * p] = f.x; sm.u.m.hv[2 * p + 1] = f.y;
      }
      if (tid < 6) sm.u.m.tv[KR + tid] = 0.f;
      __syncthreads();
      for (int it = 0; it < 5; ++it) {
        const float* src = (it & 1) ? sm.u.m.xv : sm.u.m.hv;
        float* dst = (it & 1) ? sm.u.m.hv : sm.u.m.xv;
        // stage 1: tv[j] = sum_k src[k]*U[k][j]; thread (j,q) covers k = q*8 + 64m
        if (tid < 720) {
          int j = tid >> 3, q = tid & 7;
          const unsigned short* urow = UtL + ((size_t)it * KR + j) * Hdim + q * 8;
          const float* s = src + q * 8;
          float a0 = 0.f, a1 = 0.f, a2 = 0.f, a3 = 0.f;
          #pragma unroll
          for (int m = 0; m < 8; ++m) {
            u16x8 u = *reinterpret_cast<const u16x8*>(urow + 64 * m);
            const float* sp = s + 64 * m;
            a0 += sp[0] * b2f(u[0]); a1 += sp[1] * b2f(u[1]);
            a2 += sp[2] * b2f(u[2]); a3 += sp[3] * b2f(u[3]);
            a0 += sp[4] * b2f(u[4]); a1 += sp[5] * b2f(u[5]);
            a2 += sp[6] * b2f(u[6]); a3 += sp[7] * b2f(u[7]);
          }
          float v = (a0 + a1) + (a2 + a3);
          v += __shfl_xor(v, 1);
          v += __shfl_xor(v, 2);
          v += __shfl_xor(v, 4);
          if (q == 0) sm.u.m.tv[j] = v;
        }
        __syncthreads();
        // stage 2: coalesced j-tiled V; thread = (col, j-half)
        {
          int col = tid & 511, hf = tid >> 9;
          float acc = hf ? 0.f : bm[it * Hdim + col];
          const unsigned short* vbase =
              VtL + (((size_t)it * 12 + hf * 6) * Hdim + col) * 8;
          const float* tvh = sm.u.m.tv + hf * 48;
          #pragma unroll
          for (int jt = 0; jt < 6; ++jt) {
            u16x8 v8 = *reinterpret_cast<const u16x8*>(vbase + (size_t)jt * Hdim * 8);
            const float* tp = tvh + jt * 8;
            acc += tp[0] * b2f(v8[0]) + tp[1] * b2f(v8[1])
                 + tp[2] * b2f(v8[2]) + tp[3] * b2f(v8[3])
                 + tp[4] * b2f(v8[4]) + tp[5] * b2f(v8[5])
                 + tp[6] * b2f(v8[6]) + tp[7] * b2f(v8[7]);
          }
          sm.u.m.tp2[hf][col] = acc;
        }
        __syncthreads();
        if (tid < 512) {
          float g = sm.u.m.tp2[0][tid] + sm.u.m.tp2[1][tid];
          dst[tid] *= 2.f * sigm(g);
        }
        __syncthreads();
      }
      // write act = [x(512) | h(512)] bf16, coherent u32 pairs
      unsigned* arow = reinterpret_cast<unsigned*>(act + (size_t)sub * 1024);
      if (tid < 256) {
        unsigned v = (unsigned)f2b(sm.u.m.xv[2 * tid]) |
                     ((unsigned)f2b(sm.u.m.xv[2 * tid + 1]) << 16);
        st_cohu32(arow + tid, v);
      } else if (tid < 512) {
        int t2 = tid - 256;
        unsigned v = (unsigned)f2b(sm.u.m.hv[2 * t2]) |
                     ((unsigned)f2b(sm.u.m.hv[2 * t2 + 1]) << 16);
        st_cohu32(arow + 256 + t2, v);
      }
    }
    gbar(bar);

    // ---------- phase B: LSTM (col slice = sub; 16 waves = m2 x n4 x kh2) ----------
    if (active) {
      const unsigned long long* asrc = reinterpret_cast<const unsigned long long*>(act);
      char* As = reinterpret_cast<char*>(sm.u.l.As);
      #pragma unroll
      for (int ii = 0; ii < 8; ++ii) {
        int s = tid + NTHR * ii;          // u64 index, 8192 total
        int row = s >> 8, c = s & 255;
        unsigned long long v = ld_cohu64(asrc + s);
        *reinterpret_cast<unsigned long long*>(
            As + ((row * 2048 + c * 8) ^ ((row & 7) << 4))) = v;
      }
      __syncthreads();
      const int w = tid >> 6, lane = tid & 63;
      const int m = w >> 3, n = (w >> 1) & 3, kh = w & 1;
      const int r15 = lane & 15, g = lane >> 4;
      const int arow_ = m * 16 + r15;
      const int abase = arow_ * 2048 + kh * 1024 + g * 16;
      const int aswz = (arow_ & 7) << 4;
      const unsigned short* wrow =
          W + ((size_t)(n * Hdim + sub * 16 + r15)) * 1024 + kh * 512 + 8 * g;
      f32x4 acc = {0.f, 0.f, 0.f, 0.f};
      #pragma unroll
      for (int k0 = 0; k0 < 512; k0 += 32) {
        bf16x8 af = *reinterpret_cast<const bf16x8*>(As + ((abase + 2 * k0) ^ aswz));
        bf16x8 bf = *reinterpret_cast<const bf16x8*>(wrow + k0);
        acc = __builtin_amdgcn_mfma_f32_16x16x32_bf16(af, bf, acc, 0, 0, 0);
      }
      {
        int r0 = g * 4;
        #pragma unroll
        for (int r = 0; r < 4; ++r) sm.u.l.gbuf[kh][m][n][r0 + r][r15] = acc[r];
      }
      __syncthreads();
      if (tid < 512) {
        int row = tid >> 4, col = tid & 15;
        int mm = row >> 4, lr = row & 15;
        int gc = sub * 16 + col;
        float gi = sm.u.l.gbuf[0][mm][0][lr][col] + sm.u.l.gbuf[1][mm][0][lr][col] + bs[gc];
        float gf = sm.u.l.gbuf[0][mm][1][lr][col] + sm.u.l.gbuf[1][mm][1][lr][col] + bs[512 + gc];
        float gg = sm.u.l.gbuf[0][mm][2][lr][col] + sm.u.l.gbuf[1][mm][2][lr][col] + bs[1024 + gc];
        float go = sm.u.l.gbuf[0][mm][3][lr][col] + sm.u.l.gbuf[1][mm][3][lr][col] + bs[1536 + gc];
        size_t idx = (size_t)row * Hdim + gc;
        float cn = sigm(gf) * cS[idx] + sigm(gi) * tanhf(gg);   // c: block-private, cached
        float hn = sigm(go) * tanhf(cn);
        cS[idx] = cn;
        st_cohf(hS + idx, hn);                                   // h: cross-block, coherent
        if (layer) hsb[((size_t)row * SEQ + t) * Hdim + gc] = f2b(hn);
      }
    }
    gbar(bar);
  }
}

// ---------------- output GEMM: logits = hs @ Wout^T + b ----------------
__global__ __launch_bounds__(256) void gemm_out(
    const unsigned short* __restrict__ A,
    const float* __restrict__ Wout,
    const float* __restrict__ bout,
    float* __restrict__ Cmat)
{
  __shared__ unsigned short As[128][72], Bs[128][72];
  const int Mbase = (blockIdx.x & 31) * 128;
  const int Nbase = (blockIdx.x >> 5) * 128;
  const int tid = threadIdx.x, lane = tid & 63, wid = tid >> 6;
  const int wr = wid >> 1, wc = wid & 1;
  f32x4 acc[4][4];
  #pragma unroll
  for (int m = 0; m < 4; ++m)
    #pragma unroll
    for (int n = 0; n < 4; ++n) acc[m][n] = (f32x4){0.f, 0.f, 0.f, 0.f};

  for (int kt = 0; kt < 8; ++kt) {
    const int k0 = kt * 64;
    __syncthreads();
    #pragma unroll
    for (int i = 0; i < 4; ++i) {
      int s = tid + 256 * i;
      int row = s >> 3, c8 = s & 7;
      u16x8 v = *reinterpret_cast<const u16x8*>(A + ((size_t)(Mbase + row)) * Hdim + k0 + c8 * 8);
      *reinterpret_cast<u16x8*>(&As[row][c8 * 8]) = v;
    }
    #pragma unroll
    for (int i = 0; i < 8; ++i) {
      int s = tid + 256 * i;
      int row = s >> 4, c4 = s & 15;
      float4 v = *reinterpret_cast<const float4*>(Wout + ((size_t)(Nbase + row)) * Hdim + k0 + c4 * 4);
      ushort4 b4;
      b4.x = f2b(v.x); b4.y = f2b(v.y); b4.z = f2b(v.z); b4.w = f2b(v.w);
      *reinterpret_cast<ushort4*>(&Bs[row][c4 * 4]) = b4;
    }
    __syncthreads();
    #pragma unroll
    for (int kk = 0; kk < 64; kk += 32) {
      bf16x8 af[4], bfr[4];
      #pragma unroll
      for (int m = 0; m < 4; ++m)
        af[m] = *reinterpret_cast<const bf16x8*>(&As[wr * 64 + m * 16 + (lane & 15)][kk + 8 * (lane >> 4)]);
      #pragma unroll
      for (int n = 0; n < 4; ++n)
        bfr[n] = *reinterpret_cast<const bf16x8*>(&Bs[wc * 64 + n * 16 + (lane & 15)][kk + 8 * (lane >> 4)]);
      #pragma unroll
      for (int m = 0; m < 4; ++m)
        #pragma unroll
        for (int n = 0; n < 4; ++n)
          acc[m][n] = __builtin_amdgcn_mfma_f32_16x16x32_bf16(af[m], bfr[n], acc[m][n], 0, 0, 0);
    }
  }
  const int rb = (lane >> 4) * 4, cb = lane & 15;
  #pragma unroll
  for (int m = 0; m < 4; ++m) {
    #pragma unroll
    for (int n = 0; n < 4; ++n) {
      int gc = Nbase + wc * 64 + n * 16 + cb;
      float bo = bout[gc];
      #pragma unroll
      for (int reg = 0; reg < 4; ++reg) {
        int gr = Mbase + wr * 64 + m * 16 + rb + reg;
        Cmat[(size_t)gr * VOC + gc] = acc[m][n][reg] + bo;
      }
    }
  }
}

// ---------------- in-place log_softmax over V per row ----------------
__global__ __launch_bounds__(256) void logsoftmax_kernel(float* __restrict__ out) {
  __shared__ unsigned short sl[VOC];
  __shared__ float red[8];
  const size_t base = (size_t)blockIdx.x * VOC;
  const int tid = threadIdx.x;
  float lmax = -1e30f;
  for (int i = tid; i < VOC; i += 256) {
    unsigned short ub = f2b(out[base + i]);
    sl[i] = ub;
    lmax = fmaxf(lmax, b2f(ub));
  }
  #pragma unroll
  for (int off = 32; off; off >>= 1) lmax = fmaxf(lmax, __shfl_xor(lmax, off));
  if ((tid & 63) == 0) red[tid >> 6] = lmax;
  __syncthreads();
  const float gmax = fmaxf(fmaxf(red[0], red[1]), fmaxf(red[2], red[3]));
  float lsum = 0.f;
  for (int i = tid; i < VOC; i += 256) lsum += __expf(b2f(sl[i]) - gmax);
  #pragma unroll
  for (int off = 32; off; off >>= 1) lsum += __shfl_xor(lsum, off);
  if ((tid & 63) == 0) red[4 + (tid >> 6)] = lsum;
  __syncthreads();
  const float lz = gmax + logf(red[4] + red[5] + red[6] + red[7]);
  for (int i = tid; i < VOC; i += 256) out[base + i] = b2f(sl[i]) - lz;
}

extern "C" void kernel_launch(void* const* d_in, const int* in_sizes, int n_in,
                              void* d_out, int out_size, void* d_ws, size_t ws_size,
                              hipStream_t stream) {
  const int*   tok  = (const int*)d_in[0];
  const float* emb  = (const float*)d_in[1];
  const float* Wih1 = (const float*)d_in[2];
  const float* Whh1 = (const float*)d_in[3];
  const float* bih1 = (const float*)d_in[4];
  const float* bhh1 = (const float*)d_in[5];
  const float* U1   = (const float*)d_in[6];
  const float* V1   = (const float*)d_in[7];
  const float* bm1  = (const float*)d_in[8];
  const float* Wih2 = (const float*)d_in[9];
  const float* Whh2 = (const float*)d_in[10];
  const float* bih2 = (const float*)d_in[11];
  const float* bhh2 = (const float*)d_in[12];
  const float* U2   = (const float*)d_in[13];
  const float* V2   = (const float*)d_in[14];
  const float* bm2  = (const float*)d_in[15];
  const float* Wout = (const float*)d_in[16];
  const float* bout = (const float*)d_in[17];
  float* out = (float*)d_out;
  char* ws = (char*)d_ws;

  // workspace layout
  float* h1 = (float*)(ws + 0);
  float* c1 = (float*)(ws + 65536);
  float* h2 = (float*)(ws + 131072);
  float* c2 = (float*)(ws + 196608);
  unsigned long long* bar = (unsigned long long*)(ws + 262144);  // 256 B reserved
  unsigned short* act1 = (unsigned short*)(ws + 262400);
  unsigned short* act2 = (unsigned short*)(ws + 327936);
  float* bsum = (float*)(ws + 393472);                     // [2][2048]
  unsigned short* Ut   = (unsigned short*)(ws + 409856);   // [2][5][90][512]
  unsigned short* Vt   = (unsigned short*)(ws + 1331456);  // [2][5][12][512][8]
  unsigned short* Wcat = (unsigned short*)(ws + 2314496);  // [2][2048][1024]
  unsigned short* hsb  = (unsigned short*)(ws + 10703104); // [32][128][512]

  hipMemsetAsync(d_ws, 0, 262400, stream);  // states + barrier

  cvt_transposeU<<<5 * KR, 512, 0, stream>>>(U1, Ut);
  cvt_transposeU<<<5 * KR, 512, 0, stream>>>(U2, Ut + 5 * KR * Hdim);
  cvt_transposeV<<<5 * Hdim, 128, 0, stream>>>(V1, Vt);
  cvt_transposeV<<<5 * Hdim, 128, 0, stream>>>(V2, Vt + 5 * 12 * Hdim * 8);
  cvt_wcat<<<2048, 512, 0, stream>>>(Wih1, Whh1, Wcat);
  cvt_wcat<<<2048, 512, 0, stream>>>(Wih2, Whh2, Wcat + (size_t)2048 * 1024);
  add_bias<<<8, 256, 0, stream>>>(bih1, bhh1, bsum);
  add_bias<<<8, 256, 0, stream>>>(bih2, bhh2, bsum + 2048);

  recurrence<<<NBLK, NTHR, 0, stream>>>(tok, emb, Ut, Vt, bm1, bm2, Wcat, bsum,
                                        h1, c1, h2, c2, act1, act2, hsb, bar);

  gemm_out<<<32 * (VOC / 128), 256, 0, stream>>>(hsb, Wout, bout, out);
  logsoftmax_kernel<<<BATCH * SEQ, 256, 0, stream>>>(out);
}

// Round 5
// 4651.878 us; speedup vs baseline: 3.5716x; 1.1874x over previous
//
#include <hip/hip_runtime.h>
#include <hip/hip_bf16.h>

#define Hdim 512
#define KR   90
#define KRP  96
#define BATCH 32
#define SEQ  128
#define VOC  32000
#define NBLK 64
#define NTHR 1024

typedef __attribute__((ext_vector_type(8))) short bf16x8;
typedef __attribute__((ext_vector_type(4))) float f32x4;
typedef __attribute__((ext_vector_type(8))) unsigned short u16x8;

__device__ __forceinline__ float b2f(unsigned short u) {
  union { unsigned int i; float f; } w; w.i = ((unsigned int)u) << 16; return w.f;
}
__device__ __forceinline__ unsigned short f2b(float f) {
  __hip_bfloat16 h = __float2bfloat16(f);
  return *reinterpret_cast<unsigned short*>(&h);
}
__device__ __forceinline__ float sigm(float x) { return 1.f / (1.f + expf(-x)); }

// coherent (L2-bypassing) exchange helpers — agent-scope relaxed atomics
__device__ __forceinline__ float ld_cohf(const float* p) {
  return __hip_atomic_load(p, __ATOMIC_RELAXED, __HIP_MEMORY_SCOPE_AGENT);
}
__device__ __forceinline__ void st_cohf(float* p, float v) {
  __hip_atomic_store(p, v, __ATOMIC_RELAXED, __HIP_MEMORY_SCOPE_AGENT);
}
__device__ __forceinline__ unsigned long long ld_cohu64(const unsigned long long* p) {
  return __hip_atomic_load(p, __ATOMIC_RELAXED, __HIP_MEMORY_SCOPE_AGENT);
}
__device__ __forceinline__ void st_cohu32(unsigned* p, unsigned v) {
  __hip_atomic_store(p, v, __ATOMIC_RELAXED, __HIP_MEMORY_SCOPE_AGENT);
}

// ---------------- setup: weight conversion ----------------
__global__ __launch_bounds__(512) void cvt_transposeU(const float* __restrict__ U,
                                                      unsigned short* __restrict__ Ut) {
  int i = blockIdx.x / KR, j = blockIdx.x % KR;
  int k = threadIdx.x;
  Ut[((size_t)i * KR + j) * Hdim + k] = f2b(U[((size_t)i * Hdim + k) * KR + j]);
}

// V: [5][90][512] fp32 -> Vt: [5][12][512][8] bf16 (j-tiled: coalesced across col lanes)
__global__ __launch_bounds__(128) void cvt_transposeV(const float* __restrict__ V,
                                                      unsigned short* __restrict__ Vt) {
  int i = blockIdx.x / Hdim, c = blockIdx.x % Hdim;
  int j = threadIdx.x;
  if (j < KRP) {
    float v = (j < KR) ? V[((size_t)i * KR + j) * Hdim + c] : 0.f;
    int jt = j >> 3, jj = j & 7;
    Vt[(((size_t)i * 12 + jt) * Hdim + c) * 8 + jj] = f2b(v);
  }
}

__global__ __launch_bounds__(512) void cvt_wcat(const float* __restrict__ Wih,
                                                const float* __restrict__ Whh,
                                                unsigned short* __restrict__ Wcat) {
  int r = blockIdx.x, c = threadIdx.x;
  Wcat[(size_t)r * 1024 + c]       = f2b(Wih[(size_t)r * Hdim + c]);
  Wcat[(size_t)r * 1024 + 512 + c] = f2b(Whh[(size_t)r * Hdim + c]);
}

__global__ __launch_bounds__(256) void add_bias(const float* __restrict__ a,
                                                const float* __restrict__ b,
                                                float* __restrict__ o) {
  int i = blockIdx.x * 256 + threadIdx.x;
  if (i < 2048) o[i] = a[i] + b[i];
}

// ---------------- persistent recurrence kernel ----------------
struct Smem {
  union {
    struct { float xv[512]; float hv[512]; float tv[96]; float tp2[2][512]; } m;
    struct { unsigned short As[32 * 1024]; float gbuf[4][2][4][16][17]; } l;
  } u;
};

// hierarchical monotonic barrier: 8 arrival shards (128B apart) -> master -> release.
// All relaxed agent-scope; counts never reset (gen = count/8). Store->signal ordering
// via vmcnt(0) drain before arrival.
__device__ __forceinline__ void gbar(char* barbase) {
  asm volatile("s_waitcnt vmcnt(0)" ::: "memory");
  __syncthreads();
  if (threadIdx.x == 0) {
    unsigned long long* shard =
        (unsigned long long*)(barbase + (blockIdx.x & 7) * 128);
    unsigned long long so =
        __hip_atomic_fetch_add(shard, 1ull, __ATOMIC_RELAXED, __HIP_MEMORY_SCOPE_AGENT);
    unsigned target = (unsigned)(so >> 3) + 1u;
    if ((so & 7) == 7) {
      unsigned long long* master = (unsigned long long*)(barbase + 1024);
      unsigned long long mo =
          __hip_atomic_fetch_add(master, 1ull, __ATOMIC_RELAXED, __HIP_MEMORY_SCOPE_AGENT);
      if ((mo & 7) == 7) {
        st_cohu32((unsigned*)(barbase + 1088), (unsigned)(mo >> 3) + 1u);
      }
    }
    unsigned* rel = (unsigned*)(barbase + 1088);
    while (__hip_atomic_load(rel, __ATOMIC_RELAXED, __HIP_MEMORY_SCOPE_AGENT) < target)
      __builtin_amdgcn_s_sleep(1);
  }
  __syncthreads();
}

__global__ __launch_bounds__(NTHR, 1) void recurrence(
    const int* __restrict__ tok, const float* __restrict__ emb,
    const unsigned short* __restrict__ Ut,    // [2][5][90][512]
    const unsigned short* __restrict__ Vt,    // [2][5][12][512][8]
    const float* __restrict__ bm1, const float* __restrict__ bm2,
    const unsigned short* __restrict__ Wcat,  // [2][2048][1024]
    const float* __restrict__ bsum,           // [2][2048]
    float* __restrict__ h1, float* __restrict__ c1,
    float* __restrict__ h2, float* __restrict__ c2,
    unsigned short* __restrict__ act1, unsigned short* __restrict__ act2,
    unsigned short* __restrict__ hsb,
    char* __restrict__ barbase)
{
  __shared__ Smem sm;
  const int bid = blockIdx.x, tid = threadIdx.x;
  const int layer = bid >> 5;
  const int sub = bid & 31;

  const unsigned short* UtL = Ut + (size_t)layer * 5 * KR * Hdim;
  const unsigned short* VtL = Vt + (size_t)layer * 5 * 12 * Hdim * 8;
  const float* bm = layer ? bm2 : bm1;
  const float* bs = bsum + layer * 2048;
  float* cS = layer ? c2 : c1;
  float* hS = layer ? h2 : h1;
  unsigned short* act = layer ? act2 : act1;

  // ---- W stationary in registers: wave (gate n, K-quarter kq), both m-halves ----
  const int w = tid >> 6, lane = tid & 63;
  const int n = w & 3, kq = w >> 2;
  const int r15 = lane & 15, g = lane >> 4;
  bf16x8 wreg[8];
  {
    const unsigned short* wrow = Wcat + (size_t)layer * 2048 * 1024 +
        ((size_t)(n * Hdim + sub * 16 + r15)) * 1024 + kq * 256 + g * 8;
    #pragma unroll
    for (int s = 0; s < 8; ++s)
      wreg[s] = *reinterpret_cast<const bf16x8*>(wrow + s * 32);
  }

  for (int i = 0; i <= SEQ; ++i) {
    const int t = layer ? (i - 1) : i;
    const bool active = layer ? (i >= 1) : (i < SEQ);

    // ---------- phase A: mogrifier (row = sub) ----------
    if (active) {
      if (tid < 256) {
        if (layer) {
          unsigned long long v =
              ld_cohu64((const unsigned long long*)(h1 + (size_t)sub * Hdim) + tid);
          float2 f; __builtin_memcpy(&f, &v, 8);
          sm.u.m.xv[2 * tid] = f.x; sm.u.m.xv[2 * tid + 1] = f.y;
        } else {
          float2 f = *reinterpret_cast<const float2*>(
              emb + (size_t)tok[sub * SEQ + t] * Hdim + 2 * tid);
          sm.u.m.xv[2 * tid] = f.x; sm.u.m.xv[2 * tid + 1] = f.y;
        }
      } else if (tid < 512) {
        int p = tid - 256;
        unsigned long long v =
            ld_cohu64((const unsigned long long*)(hS + (size_t)sub * Hdim) + p);
        float2 f; __builtin_memcpy(&f, &v, 8);
        sm.u.m.hv[2 * p] = f.x; sm.u.m.hv[2 * p + 1] = f.y;
      }
      if (tid < 6) sm.u.m.tv[KR + tid] = 0.f;
      __syncthreads();
      for (int it = 0; it < 5; ++it) {
        const float* src = (it & 1) ? sm.u.m.xv : sm.u.m.hv;
        float* dst = (it & 1) ? sm.u.m.hv : sm.u.m.xv;
        // stage 1: tv[j] = sum_k src[k]*U[k][j]; thread (j,q) covers k = q*8 + 64m
        if (tid < 720) {
          int j = tid >> 3, q = tid & 7;
          const unsigned short* urow = UtL + ((size_t)it * KR + j) * Hdim + q * 8;
          const float* s = src + q * 8;
          float a0 = 0.f, a1 = 0.f, a2 = 0.f, a3 = 0.f;
          #pragma unroll
          for (int m = 0; m < 8; ++m) {
            u16x8 u = *reinterpret_cast<const u16x8*>(urow + 64 * m);
            const float* sp = s + 64 * m;
            a0 += sp[0] * b2f(u[0]); a1 += sp[1] * b2f(u[1]);
            a2 += sp[2] * b2f(u[2]); a3 += sp[3] * b2f(u[3]);
            a0 += sp[4] * b2f(u[4]); a1 += sp[5] * b2f(u[5]);
            a2 += sp[6] * b2f(u[6]); a3 += sp[7] * b2f(u[7]);
          }
          float v = (a0 + a1) + (a2 + a3);
          v += __shfl_xor(v, 1);
          v += __shfl_xor(v, 2);
          v += __shfl_xor(v, 4);
          if (q == 0) sm.u.m.tv[j] = v;
        }
        __syncthreads();
        // stage 2: coalesced j-tiled V; thread = (col, j-half)
        {
          int col = tid & 511, hf = tid >> 9;
          float acc = hf ? 0.f : bm[it * Hdim + col];
          const unsigned short* vbase =
              VtL + (((size_t)it * 12 + hf * 6) * Hdim + col) * 8;
          const float* tvh = sm.u.m.tv + hf * 48;
          #pragma unroll
          for (int jt = 0; jt < 6; ++jt) {
            u16x8 v8 = *reinterpret_cast<const u16x8*>(vbase + (size_t)jt * Hdim * 8);
            const float* tp = tvh + jt * 8;
            acc += tp[0] * b2f(v8[0]) + tp[1] * b2f(v8[1])
                 + tp[2] * b2f(v8[2]) + tp[3] * b2f(v8[3])
                 + tp[4] * b2f(v8[4]) + tp[5] * b2f(v8[5])
                 + tp[6] * b2f(v8[6]) + tp[7] * b2f(v8[7]);
          }
          sm.u.m.tp2[hf][col] = acc;
        }
        __syncthreads();
        if (tid < 512) {
          float gt = sm.u.m.tp2[0][tid] + sm.u.m.tp2[1][tid];
          dst[tid] *= 2.f * sigm(gt);
        }
        __syncthreads();
      }
      // write act = [x(512) | h(512)] bf16, coherent u32 pairs
      unsigned* arow = reinterpret_cast<unsigned*>(act + (size_t)sub * 1024);
      if (tid < 256) {
        unsigned v = (unsigned)f2b(sm.u.m.xv[2 * tid]) |
                     ((unsigned)f2b(sm.u.m.xv[2 * tid + 1]) << 16);
        st_cohu32(arow + tid, v);
      } else if (tid < 512) {
        int t2 = tid - 256;
        unsigned v = (unsigned)f2b(sm.u.m.hv[2 * t2]) |
                     ((unsigned)f2b(sm.u.m.hv[2 * t2 + 1]) << 16);
        st_cohu32(arow + 256 + t2, v);
      }
    }
    gbar(barbase);

    // ---------- phase B: LSTM (col slice = sub; waves = gate n x K-quarter kq) ----------
    if (active) {
      const unsigned long long* asrc = reinterpret_cast<const unsigned long long*>(act);
      char* As = reinterpret_cast<char*>(sm.u.l.As);
      #pragma unroll
      for (int ii = 0; ii < 8; ++ii) {
        int s = tid + NTHR * ii;          // u64 index, 8192 total
        int row = s >> 8, c = s & 255;
        unsigned long long v = ld_cohu64(asrc + s);
        *reinterpret_cast<unsigned long long*>(
            As + ((row * 2048 + c * 8) ^ ((row & 7) << 4))) = v;
      }
      __syncthreads();
      f32x4 accA = {0.f, 0.f, 0.f, 0.f}, accB = {0.f, 0.f, 0.f, 0.f};
      #pragma unroll
      for (int s = 0; s < 8; ++s) {
        const int kb = kq * 512 + s * 64 + g * 16;   // byte offset of k-chunk
        const int rowA = r15, rowB = 16 + r15;
        bf16x8 afA = *reinterpret_cast<const bf16x8*>(
            As + ((rowA * 2048 + kb) ^ ((rowA & 7) << 4)));
        bf16x8 afB = *reinterpret_cast<const bf16x8*>(
            As + ((rowB * 2048 + kb) ^ ((rowB & 7) << 4)));
        accA = __builtin_amdgcn_mfma_f32_16x16x32_bf16(afA, wreg[s], accA, 0, 0, 0);
        accB = __builtin_amdgcn_mfma_f32_16x16x32_bf16(afB, wreg[s], accB, 0, 0, 0);
      }
      {
        int r0 = g * 4;
        #pragma unroll
        for (int r = 0; r < 4; ++r) {
          sm.u.l.gbuf[kq][0][n][r0 + r][r15] = accA[r];
          sm.u.l.gbuf[kq][1][n][r0 + r][r15] = accB[r];
        }
      }
      __syncthreads();
      if (tid < 512) {
        int row = tid >> 4, col = tid & 15;
        int mm = row >> 4, lr = row & 15;
        int gc = sub * 16 + col;
        float gi = sm.u.l.gbuf[0][mm][0][lr][col] + sm.u.l.gbuf[1][mm][0][lr][col]
                 + sm.u.l.gbuf[2][mm][0][lr][col] + sm.u.l.gbuf[3][mm][0][lr][col] + bs[gc];
        float gf = sm.u.l.gbuf[0][mm][1][lr][col] + sm.u.l.gbuf[1][mm][1][lr][col]
                 + sm.u.l.gbuf[2][mm][1][lr][col] + sm.u.l.gbuf[3][mm][1][lr][col] + bs[512 + gc];
        float gg = sm.u.l.gbuf[0][mm][2][lr][col] + sm.u.l.gbuf[1][mm][2][lr][col]
                 + sm.u.l.gbuf[2][mm][2][lr][col] + sm.u.l.gbuf[3][mm][2][lr][col] + bs[1024 + gc];
        float go = sm.u.l.gbuf[0][mm][3][lr][col] + sm.u.l.gbuf[1][mm][3][lr][col]
                 + sm.u.l.gbuf[2][mm][3][lr][col] + sm.u.l.gbuf[3][mm][3][lr][col] + bs[1536 + gc];
        size_t idx = (size_t)row * Hdim + gc;
        float cn = sigm(gf) * cS[idx] + sigm(gi) * tanhf(gg);   // c: block-private, cached
        float hn = sigm(go) * tanhf(cn);
        cS[idx] = cn;
        st_cohf(hS + idx, hn);                                   // h: cross-block, coherent
        if (layer) hsb[((size_t)row * SEQ + t) * Hdim + gc] = f2b(hn);
      }
    }
    gbar(barbase);
  }
}

// ---------------- output GEMM: logits = hs @ Wout^T + b ----------------
__global__ __launch_bounds__(256) void gemm_out(
    const unsigned short* __restrict__ A,
    const float* __restrict__ Wout,
    const float* __restrict__ bout,
    float* __restrict__ Cmat)
{
  __shared__ unsigned short As[128][72], Bs[128][72];
  const int Mbase = (blockIdx.x & 31) * 128;
  const int Nbase = (blockIdx.x >> 5) * 128;
  const int tid = threadIdx.x, lane = tid & 63, wid = tid >> 6;
  const int wr = wid >> 1, wc = wid & 1;
  f32x4 acc[4][4];
  #pragma unroll
  for (int m = 0; m < 4; ++m)
    #pragma unroll
    for (int n = 0; n < 4; ++n) acc[m][n] = (f32x4){0.f, 0.f, 0.f, 0.f};

  for (int kt = 0; kt < 8; ++kt) {
    const int k0 = kt * 64;
    __syncthreads();
    #pragma unroll
    for (int i = 0; i < 4; ++i) {
      int s = tid + 256 * i;
      int row = s >> 3, c8 = s & 7;
      u16x8 v = *reinterpret_cast<const u16x8*>(A + ((size_t)(Mbase + row)) * Hdim + k0 + c8 * 8);
      *reinterpret_cast<u16x8*>(&As[row][c8 * 8]) = v;
    }
    #pragma unroll
    for (int i = 0; i < 8; ++i) {
      int s = tid + 256 * i;
      int row = s >> 4, c4 = s & 15;
      float4 v = *reinterpret_cast<const float4*>(Wout + ((size_t)(Nbase + row)) * Hdim + k0 + c4 * 4);
      ushort4 b4;
      b4.x = f2b(v.x); b4.y = f2b(v.y); b4.z = f2b(v.z); b4.w = f2b(v.w);
      *reinterpret_cast<ushort4*>(&Bs[row][c4 * 4]) = b4;
    }
    __syncthreads();
    #pragma unroll
    for (int kk = 0; kk < 64; kk += 32) {
      bf16x8 af[4], bfr[4];
      #pragma unroll
      for (int m = 0; m < 4; ++m)
        af[m] = *reinterpret_cast<const bf16x8*>(&As[wr * 64 + m * 16 + (lane & 15)][kk + 8 * (lane >> 4)]);
      #pragma unroll
      for (int n = 0; n < 4; ++n)
        bfr[n] = *reinterpret_cast<const bf16x8*>(&Bs[wc * 64 + n * 16 + (lane & 15)][kk + 8 * (lane >> 4)]);
      #pragma unroll
      for (int m = 0; m < 4; ++m)
        #pragma unroll
        for (int n = 0; n < 4; ++n)
          acc[m][n] = __builtin_amdgcn_mfma_f32_16x16x32_bf16(af[m], bfr[n], acc[m][n], 0, 0, 0);
    }
  }
  const int rb = (lane >> 4) * 4, cb = lane & 15;
  #pragma unroll
  for (int m = 0; m < 4; ++m) {
    #pragma unroll
    for (int n = 0; n < 4; ++n) {
      int gc = Nbase + wc * 64 + n * 16 + cb;
      float bo = bout[gc];
      #pragma unroll
      for (int reg = 0; reg < 4; ++reg) {
        int gr = Mbase + wr * 64 + m * 16 + rb + reg;
        Cmat[(size_t)gr * VOC + gc] = acc[m][n][reg] + bo;
      }
    }
  }
}

// ---------------- in-place log_softmax over V per row ----------------
__global__ __launch_bounds__(256) void logsoftmax_kernel(float* __restrict__ out) {
  __shared__ unsigned short sl[VOC];
  __shared__ float red[8];
  const size_t base = (size_t)blockIdx.x * VOC;
  const int tid = threadIdx.x;
  float lmax = -1e30f;
  for (int i = tid; i < VOC; i += 256) {
    unsigned short ub = f2b(out[base + i]);
    sl[i] = ub;
    lmax = fmaxf(lmax, b2f(ub));
  }
  #pragma unroll
  for (int off = 32; off; off >>= 1) lmax = fmaxf(lmax, __shfl_xor(lmax, off));
  if ((tid & 63) == 0) red[tid >> 6] = lmax;
  __syncthreads();
  const float gmax = fmaxf(fmaxf(red[0], red[1]), fmaxf(red[2], red[3]));
  float lsum = 0.f;
  for (int i = tid; i < VOC; i += 256) lsum += __expf(b2f(sl[i]) - gmax);
  #pragma unroll
  for (int off = 32; off; off >>= 1) lsum += __shfl_xor(lsum, off);
  if ((tid & 63) == 0) red[4 + (tid >> 6)] = lsum;
  __syncthreads();
  const float lz = gmax + logf(red[4] + red[5] + red[6] + red[7]);
  for (int i = tid; i < VOC; i += 256) out[base + i] = b2f(sl[i]) - lz;
}

extern "C" void kernel_launch(void* const* d_in, const int* in_sizes, int n_in,
                              void* d_out, int out_size, void* d_ws, size_t ws_size,
                              hipStream_t stream) {
  const int*   tok  = (const int*)d_in[0];
  const float* emb  = (const float*)d_in[1];
  const float* Wih1 = (const float*)d_in[2];
  const float* Whh1 = (const float*)d_in[3];
  const float* bih1 = (const float*)d_in[4];
  const float* bhh1 = (const float*)d_in[5];
  const float* U1   = (const float*)d_in[6];
  const float* V1   = (const float*)d_in[7];
  const float* bm1  = (const float*)d_in[8];
  const float* Wih2 = (const float*)d_in[9];
  const float* Whh2 = (const float*)d_in[10];
  const float* bih2 = (const float*)d_in[11];
  const float* bhh2 = (const float*)d_in[12];
  const float* U2   = (const float*)d_in[13];
  const float* V2   = (const float*)d_in[14];
  const float* bm2  = (const float*)d_in[15];
  const float* Wout = (const float*)d_in[16];
  const float* bout = (const float*)d_in[17];
  float* out = (float*)d_out;
  char* ws = (char*)d_ws;

  // workspace layout
  float* h1 = (float*)(ws + 0);
  float* c1 = (float*)(ws + 65536);
  float* h2 = (float*)(ws + 131072);
  float* c2 = (float*)(ws + 196608);
  char* bar = ws + 262144;                                 // 4096 B barrier region
  unsigned short* act1 = (unsigned short*)(ws + 266240);
  unsigned short* act2 = (unsigned short*)(ws + 331776);
  float* bsum = (float*)(ws + 397312);                     // [2][2048]
  unsigned short* Ut   = (unsigned short*)(ws + 413696);   // [2][5][90][512]
  unsigned short* Vt   = (unsigned short*)(ws + 1335296);  // [2][5][12][512][8]
  unsigned short* Wcat = (unsigned short*)(ws + 2318336);  // [2][2048][1024]
  unsigned short* hsb  = (unsigned short*)(ws + 10706944); // [32][128][512]

  hipMemsetAsync(d_ws, 0, 266240, stream);  // states + barrier

  cvt_transposeU<<<5 * KR, 512, 0, stream>>>(U1, Ut);
  cvt_transposeU<<<5 * KR, 512, 0, stream>>>(U2, Ut + 5 * KR * Hdim);
  cvt_transposeV<<<5 * Hdim, 128, 0, stream>>>(V1, Vt);
  cvt_transposeV<<<5 * Hdim, 128, 0, stream>>>(V2, Vt + 5 * 12 * Hdim * 8);
  cvt_wcat<<<2048, 512, 0, stream>>>(Wih1, Whh1, Wcat);
  cvt_wcat<<<2048, 512, 0, stream>>>(Wih2, Whh2, Wcat + (size_t)2048 * 1024);
  add_bias<<<8, 256, 0, stream>>>(bih1, bhh1, bsum);
  add_bias<<<8, 256, 0, stream>>>(bih2, bhh2, bsum + 2048);

  recurrence<<<NBLK, NTHR, 0, stream>>>(tok, emb, Ut, Vt, bm1, bm2, Wcat, bsum,
                                        h1, c1, h2, c2, act1, act2, hsb, bar);

  gemm_out<<<32 * (VOC / 128), 256, 0, stream>>>(hsb, Wout, bout, out);
  logsoftmax_kernel<<<BATCH * SEQ, 256, 0, stream>>>(out);
}